// Round 7
// baseline (188.830 us; speedup 1.0000x reference)
//
#include <hip/hip_runtime.h>
#include <math.h>

#define B_ 8
#define S_ 512
#define D_ 512
#define WIDTH_ 16
#define NSEQ 544                 // S + 2*WIDTH
#define MROWS 4352               // B*NSEQ
#define MOUT 4096                // B*S
#define OUTHALF 4194304          // B*S*2D floats per output tensor

typedef _Float16 half8 __attribute__((ext_vector_type(8)));
typedef _Float16 half4 __attribute__((ext_vector_type(4)));
typedef float floatx4 __attribute__((ext_vector_type(4)));

// async global->LDS, 16B per lane, dest = wave-uniform base + lane*16
#define GLD16(g, l) __builtin_amdgcn_global_load_lds(                          \
    (const __attribute__((address_space(1))) void*)(g),                        \
    (__attribute__((address_space(3))) void*)(l), 16, 0, 0)

#define WAIT_VM(n)  asm volatile("s_waitcnt vmcnt(" #n ")" ::: "memory")
#define WAIT_LGKM0() asm volatile("s_waitcnt lgkmcnt(0)" ::: "memory")
#define BARRIER()                                                              \
    do {                                                                       \
        __builtin_amdgcn_s_barrier();                                          \
        asm volatile("" ::: "memory");                                         \
    } while (0)

__device__ __forceinline__ float sigmoidf_(float x) {
    return 1.f / (1.f + __expf(-x));
}

// XCD-contiguity swizzle: dispatch index d (round-robin over 8 XCDs) ->
// logical tile t = (d%8)*(nwg/8) + d/8 so each XCD gets a contiguous chunk.
// All grids here have nwg % 8 == 0 (bijective).
__device__ __forceinline__ void xcd_swz(const int nx, const int ny,
                                        int& bx, int& by, int& bz) {
    const int flat = blockIdx.x + nx * (blockIdx.y + ny * blockIdx.z);
    const int nwg  = nx * ny * 2;
    const int t2   = (flat & 7) * (nwg >> 3) + (flat >> 3);
    bz = t2 / (nx * ny);
    const int rem = t2 - bz * nx * ny;
    by = rem / nx;
    bx = rem - by * nx;
}

// ================= QKV GEMM: 128x128 tile, f16 out, dual-dir =================
// grid (12, 34, 2), block 256.  R3-proven loop: double-buffered, depth-2
// counted vmcnt, two barriers/phase.  Epilogue: C-tile in LDS -> half8 stores.
__global__ __launch_bounds__(256)
void gemm_qkv(const _Float16* __restrict__ A,
              const _Float16* __restrict__ B0, const _Float16* __restrict__ B1,
              const float* __restrict__ bias0, const float* __restrict__ bias1,
              _Float16* __restrict__ C16) {
    const int lda = 512, ldb = 512, ldc = 1536;
    __shared__ _Float16 SH[16384];   // 32 KB: A @0/4096, B @8192/12288; CT reuse
    int bx, by, bz;
    xcd_swz(12, 34, bx, by, bz);
    const int t    = threadIdx.x;
    const int wave = t >> 6;
    const int lane = t & 63;
    const int bm = by * 128;
    const int bn = bx * 128;
    const int z  = bz;
    const _Float16* B = z ? B1 : B0;
    const float* bias = z ? bias1 : bias0;
    _Float16* C = C16 + (size_t)z * MROWS * 1536;
    const int wm = (wave & 1) * 64;
    const int wn = (wave >> 1) * 64;

    const int inst = wave * 2;
    const int r0 = inst * 16 + (lane >> 2);   // 16 rows per GLD16 inst
    const int kf = (lane & 3) * 8;

    const _Float16* Ag0 = A + (size_t)(bm + r0) * lda + kf;
    const _Float16* Ag1 = Ag0 + (size_t)16 * lda;
    const _Float16* Bg0 = B + (size_t)(bn + r0) * ldb + kf;
    const _Float16* Bg1 = Bg0 + (size_t)16 * ldb;
    const int so = inst * 512;                // f16 offset inside one buffer

    const int fr = lane & 15;
    const int fq = (lane >> 4) * 8;

    floatx4 acc[4][4] = {};

#define QKV_STAGE(bf_, koff_)                                                  \
    do {                                                                       \
        GLD16(Ag0 + (koff_), &SH[(bf_) * 4096 + so]);                          \
        GLD16(Ag1 + (koff_), &SH[(bf_) * 4096 + so + 512]);                    \
        GLD16(Bg0 + (koff_), &SH[8192 + (bf_) * 4096 + so]);                   \
        GLD16(Bg1 + (koff_), &SH[8192 + (bf_) * 4096 + so + 512]);             \
    } while (0)

    QKV_STAGE(0, 0);
    QKV_STAGE(1, 32);

#pragma unroll
    for (int tt = 0; tt < 16; tt++) {
        const int c = tt & 1;
        if (tt == 15) WAIT_VM(0);   // no future tile staged: drain fully
        else          WAIT_VM(4);   // buf c's 4 loads done; next tile's fly
        BARRIER();
        half8 af[4], bf[4];
#pragma unroll
        for (int s = 0; s < 4; s++) {
            af[s] = *(const half8*)&SH[c * 4096 + (wm + s * 16 + fr) * 32 + fq];
            bf[s] = *(const half8*)&SH[8192 + c * 4096 + (wn + s * 16 + fr) * 32 + fq];
        }
        WAIT_LGKM0();               // my reads of buf c done
        BARRIER();                  // everyone's reads done -> safe to overwrite
        if (tt + 2 < 16) QKV_STAGE(c, (tt + 2) * 32);
#pragma unroll
        for (int i = 0; i < 4; i++)
#pragma unroll
            for (int j = 0; j < 4; j++)
                acc[i][j] = __builtin_amdgcn_mfma_f32_16x16x32_f16(
                    af[i], bf[j], acc[i][j], 0, 0, 0);
    }
#undef QKV_STAGE

    // ---- coalesced epilogue: acc -> LDS (f16, +bias) -> half8 stores ----
    const int rq = (lane >> 4) * 4;
    const int cc = lane & 15;
#pragma unroll
    for (int i = 0; i < 4; i++) {
#pragma unroll
        for (int j = 0; j < 4; j++) {
            const int col = wn + j * 16 + cc;
            const float bv = bias[bn + col];
#pragma unroll
            for (int r = 0; r < 4; r++)
                SH[(wm + i * 16 + rq + r) * 128 + col] =
                    (_Float16)(acc[i][j][r] + bv);
        }
    }
    WAIT_LGKM0();
    BARRIER();
#pragma unroll
    for (int it = 0; it < 8; it++) {
        const int flat = it * 256 + t;
        const int row = flat >> 4;
        const int ch  = flat & 15;
        *(half8*)&C[(size_t)(bm + row) * ldc + bn + ch * 8] =
            *(const half8*)&SH[row * 128 + ch * 8];
    }
}

// ======== Wo GEMM: 64x128 tile, dual-dir, fused slice epilogue ========
// grid (4, 68, 2), block 256.  R3-exact (incl. direct sliced scalar stores).
__global__ __launch_bounds__(256)
void gemm_wo(const _Float16* __restrict__ Aall,
             const _Float16* __restrict__ B0, const _Float16* __restrict__ B1,
             const float* __restrict__ bias0, const float* __restrict__ bias1,
             _Float16* __restrict__ x16base) { // +z*MOUT*512
    const int lda = 512, ldb = 512;
    __shared__ _Float16 As[2][64 * 32];     // 8 KB
    __shared__ _Float16 Bs[2][128 * 32];    // 16 KB
    int bx, by, bz;
    xcd_swz(4, 68, bx, by, bz);
    const int t    = threadIdx.x;
    const int wave = t >> 6;
    const int lane = t & 63;
    const int bm = by * 64;
    const int bn = bx * 128;
    const int z  = bz;
    const _Float16* A = Aall + (size_t)z * MROWS * 512;
    const _Float16* B = z ? B1 : B0;
    const float* bias = z ? bias1 : bias0;
    _Float16* x16 = x16base + (size_t)z * MOUT * 512;

    const int wm = (wave & 1) * 32;
    const int wn = (wave >> 1) * 64;

    const int rA = wave * 16 + (lane >> 2);
    const int rB = wave * 32 + (lane >> 2);
    const int kf = (lane & 3) * 8;

    const _Float16* Ag0 = A + (size_t)(bm + rA) * lda + kf;
    const _Float16* Bg0 = B + (size_t)(bn + rB) * ldb + kf;
    const _Float16* Bg1 = Bg0 + (size_t)16 * ldb;
    const int soA = wave * 512;
    const int soB = wave * 1024;

    const int fr = lane & 15;
    const int fq = (lane >> 4) * 8;

    floatx4 acc[2][4] = {};

#define WO_STAGE(bf_, koff_)                                                   \
    do {                                                                       \
        GLD16(Ag0 + (koff_), &As[bf_][soA]);                                   \
        GLD16(Bg0 + (koff_), &Bs[bf_][soB]);                                   \
        GLD16(Bg1 + (koff_), &Bs[bf_][soB + 512]);                             \
    } while (0)

    WO_STAGE(0, 0);
    WO_STAGE(1, 32);

#pragma unroll
    for (int tt = 0; tt < 16; tt++) {
        const int c = tt & 1;
        if (tt == 15) WAIT_VM(0);
        else          WAIT_VM(3);
        BARRIER();
        half8 af[2], bf[4];
#pragma unroll
        for (int s = 0; s < 2; s++)
            af[s] = *(const half8*)&As[c][(wm + s * 16 + fr) * 32 + fq];
#pragma unroll
        for (int s = 0; s < 4; s++)
            bf[s] = *(const half8*)&Bs[c][(wn + s * 16 + fr) * 32 + fq];
        WAIT_LGKM0();
        BARRIER();
        if (tt + 2 < 16) WO_STAGE(c, (tt + 2) * 32);
#pragma unroll
        for (int i = 0; i < 2; i++)
#pragma unroll
            for (int j = 0; j < 4; j++)
                acc[i][j] = __builtin_amdgcn_mfma_f32_16x16x32_f16(
                    af[i], bf[j], acc[i][j], 0, 0, 0);
    }
#undef WO_STAGE

    const int rq = (lane >> 4) * 4;
    const int cc = lane & 15;
#pragma unroll
    for (int i = 0; i < 2; i++) {
        const int rbase = bm + wm + i * 16 + rq;
#pragma unroll
        for (int r = 0; r < 4; r++) {
            const int row = rbase + r;
            const int b = row / NSEQ;
            const int s = row - b * NSEQ;
            if (s < WIDTH_ || s >= WIDTH_ + S_) continue;
            const int m = b * S_ + s - WIDTH_;
#pragma unroll
            for (int j = 0; j < 4; j++) {
                const int col = bn + wn + j * 16 + cc;
                x16[(size_t)m * 512 + col] = (_Float16)(acc[i][j][r] + bias[col]);
            }
        }
    }
}

// ==== Highway GEMM: 128x128 tile, 512 threads, dual-N, fused combine ====
// grid (4, 32, 2) = 256 blocks (exactly 1/CU, no tail).  nx=8 -> nx=4 halves
// the A-panel re-reads (67 -> 34 MB per dispatch).  8 waves (2 row x 4 col),
// 3 GLD16/wave/phase, 48 KB LDS, R3 two-barrier depth-2 loop.
__global__ __launch_bounds__(512)
void gemm_hw(const _Float16* __restrict__ x16inbase,
             const _Float16* __restrict__ W0, const _Float16* __restrict__ W1,
             const float* __restrict__ b0, const float* __restrict__ b1,
             _Float16* __restrict__ x16outbase,   // null on last layer
             float* __restrict__ outlastbase,     // last layer only
             float* __restrict__ outallbase) {    // last layer only
    __shared__ _Float16 SH[24576];   // 48 KB: A @0/4096, Bn @8192/12288, Bg @16384/20480
    int bx, by, bz;
    xcd_swz(4, 32, bx, by, bz);
    const int t    = threadIdx.x;
    const int wave = t >> 6;        // 0..7
    const int lane = t & 63;
    const int bm = by * 128;
    const int bn = bx * 128;        // col block within [0,512)
    const int z  = bz;
    const _Float16* A = x16inbase + (size_t)z * MOUT * 512;
    const _Float16* W = z ? W1 : W0;
    const float* bias = z ? b1 : b0;
    _Float16* x16out = x16outbase ? x16outbase + (size_t)z * MOUT * 512 : nullptr;

    const int wm = (wave & 1) * 64;
    const int wn = (wave >> 1) * 32;

    const int rS = wave * 16 + (lane >> 2);   // staging rows: wave covers 16
    const int kf = (lane & 3) * 8;

    const _Float16* Ag0 = A + (size_t)(bm + rS) * 512 + kf;
    const _Float16* Bn0 = W + (size_t)(bn + rS) * 512 + kf;          // nl rows
    const _Float16* Bg0 = W + (size_t)(512 + bn + rS) * 512 + kf;    // gate rows
    const int so = wave * 512;

    const int fr = lane & 15;
    const int fq = (lane >> 4) * 8;

    floatx4 accn[4][2] = {};
    floatx4 accg[4][2] = {};

#define HW_STAGE(bf_, koff_)                                                   \
    do {                                                                       \
        GLD16(Ag0 + (koff_), &SH[(bf_) * 4096 + so]);                          \
        GLD16(Bn0 + (koff_), &SH[8192 + (bf_) * 4096 + so]);                   \
        GLD16(Bg0 + (koff_), &SH[16384 + (bf_) * 4096 + so]);                  \
    } while (0)

    HW_STAGE(0, 0);
    HW_STAGE(1, 32);

#pragma unroll
    for (int tt = 0; tt < 16; tt++) {
        const int c = tt & 1;
        if (tt == 15) WAIT_VM(0);
        else          WAIT_VM(3);
        BARRIER();
        half8 af[4], bnf[2], bgf[2];
#pragma unroll
        for (int s = 0; s < 4; s++)
            af[s] = *(const half8*)&SH[c * 4096 + (wm + s * 16 + fr) * 32 + fq];
#pragma unroll
        for (int s = 0; s < 2; s++) {
            bnf[s] = *(const half8*)&SH[8192 + c * 4096 + (wn + s * 16 + fr) * 32 + fq];
            bgf[s] = *(const half8*)&SH[16384 + c * 4096 + (wn + s * 16 + fr) * 32 + fq];
        }
        WAIT_LGKM0();
        BARRIER();
        if (tt + 2 < 16) HW_STAGE(c, (tt + 2) * 32);
#pragma unroll
        for (int i = 0; i < 4; i++)
#pragma unroll
            for (int j = 0; j < 2; j++) {
                accn[i][j] = __builtin_amdgcn_mfma_f32_16x16x32_f16(
                    af[i], bnf[j], accn[i][j], 0, 0, 0);
                accg[i][j] = __builtin_amdgcn_mfma_f32_16x16x32_f16(
                    af[i], bgf[j], accg[i][j], 0, 0, 0);
            }
    }
#undef HW_STAGE

    const int rq = (lane >> 4) * 4;
    const int cc = lane & 15;
    if (x16out) {
        // combine -> LDS f16 tile [128][128] -> coalesced half8 stores
#pragma unroll
        for (int i = 0; i < 4; i++) {
#pragma unroll
            for (int j = 0; j < 2; j++) {
                const int col = wn + j * 16 + cc;
                const float bnl = bias[bn + col];
                const float bgt = bias[512 + bn + col];
#pragma unroll
                for (int r = 0; r < 4; r++) {
                    const int row = wm + i * 16 + rq + r;
                    const float nl = fmaxf(accn[i][j][r] + bnl, 0.f);
                    const float g  = sigmoidf_(accg[i][j][r] + bgt);
                    const float xo = (float)A[(size_t)(bm + row) * 512 + bn + col];
                    SH[row * 128 + col] = (_Float16)(g * xo + (1.f - g) * nl);
                }
            }
        }
        WAIT_LGKM0();
        BARRIER();
#pragma unroll
        for (int it = 0; it < 4; it++) {
            const int flat = it * 512 + t;
            const int row = flat >> 4;
            const int ch  = flat & 15;
            *(half8*)&x16out[(size_t)(bm + row) * 512 + bn + ch * 8] =
                *(const half8*)&SH[row * 128 + ch * 8];
        }
    } else {
        // layer 2: direct f32 stores (R3-proven; staging was null in R6)
        float* outlast = outlastbase + z * 512;
        float* outall  = outallbase  + z * 512;
#pragma unroll
        for (int i = 0; i < 4; i++) {
            const int rbase = bm + wm + i * 16 + rq;
#pragma unroll
            for (int j = 0; j < 2; j++) {
                const int col = bn + wn + j * 16 + cc;
                const float bnl = bias[col];
                const float bgt = bias[512 + col];
#pragma unroll
                for (int r = 0; r < 4; r++) {
                    const int row = rbase + r;
                    const float nl = fmaxf(accn[i][j][r] + bnl, 0.f);
                    const float g  = sigmoidf_(accg[i][j][r] + bgt);
                    const float xo = (float)A[(size_t)row * 512 + col - bn + bn];
                    const float v  = g * xo + (1.f - g) * nl;
                    outlast[(size_t)row * 1024 + col] = v;
                    outall[(size_t)row * 1024 + col] = v;
                }
            }
        }
    }
}

// ---------- windowed attention, dual-dir, TI=8 query-sliding window ----------
// Thread = (dir, b, head, 8 consecutive queries).  Loads 25 K/V rows instead
// of 42 (2x TI=4's per-query traffic cut; 93 -> 55 MB cache reads).  Per-query
// jj order identical to TI=4 -> bitwise-same output.  grid 272 x 256.
__global__ __launch_bounds__(256)
void attn_win(const _Float16* __restrict__ qkvall, _Float16* __restrict__ attall) {
    const int sb  = (blockIdx.x & 7) * 34 + (blockIdx.x >> 3);   // XCD swizzle
    const int wid = threadIdx.x >> 6;
    const int h   = threadIdx.x & 63;
    const int wflat = sb * 4 + wid;          // 0..1087
    const int ig  = wflat % 68;
    const int db  = wflat / 68;              // 0..15
    const int b   = db & 7;
    const int dir = db >> 3;
    const int i0  = ig * 8;
    const int dlo = dir ? 0 : -17;
    const _Float16* qkv = qkvall + (size_t)dir * MROWS * 1536;
    _Float16* att = attall + (size_t)dir * MROWS * 512;
    const size_t rowb = (size_t)b * NSEQ;
    const float scale = 0.35355339059327373f;  // 1/sqrt(8)

    float q[8][8];
#pragma unroll
    for (int tq = 0; tq < 8; tq++) {
        const half8 q8 = *(const half8*)(qkv + (rowb + i0 + tq) * 1536 + h * 8);
#pragma unroll
        for (int d = 0; d < 8; d++) q[tq][d] = (float)q8[d];
    }

    float o[8][8] = {};
    float sum[8] = {};
    const int j0 = i0 + dlo;

#pragma unroll
    for (int jj = 0; jj < 25; jj++) {
        const int j = j0 + jj;
        if (j < 0 || j > NSEQ - 1) continue;   // wave-uniform branch
        const size_t jbase = (rowb + j) * 1536 + h * 8;
        const half8 k8 = *(const half8*)(qkv + jbase + 512);
        const half8 v8 = *(const half8*)(qkv + jbase + 1024);
        float kv[8], vv[8];
#pragma unroll
        for (int d = 0; d < 8; d++) { kv[d] = (float)k8[d]; vv[d] = (float)v8[d]; }
#pragma unroll
        for (int tq = 0; tq < 8; tq++) {
            if (jj < tq || jj > tq + 17) continue;  // compile-time prune
            float d = 0.f;
#pragma unroll
            for (int dd = 0; dd < 8; dd++) d = fmaf(q[tq][dd], kv[dd], d);
            const float p = __expf(d * scale);   // shift-free softmax (s is O(1))
            sum[tq] += p;
#pragma unroll
            for (int dd = 0; dd < 8; dd++) o[tq][dd] = fmaf(p, vv[dd], o[tq][dd]);
        }
    }

#pragma unroll
    for (int tq = 0; tq < 8; tq++) {
        const float inv = 1.f / sum[tq];
        half8 o16;
#pragma unroll
        for (int d = 0; d < 8; d++) o16[d] = (_Float16)(o[tq][d] * inv);
        *(half8*)&att[(rowb + i0 + tq) * 512 + h * 8] = o16;
    }
}

// ====== prep: fused weight convert (6 tensors) + pad-concat to f16 ======
__global__ void prep(const float* __restrict__ lq, const float* __restrict__ rq,
                     const float* __restrict__ lo, const float* __restrict__ ro,
                     const float* __restrict__ lh, const float* __restrict__ rh,
                     _Float16* __restrict__ wdst,
                     const float* __restrict__ inp,
                     const float* __restrict__ lp,
                     const float* __restrict__ rp,
                     _Float16* __restrict__ padX) {
    const int gb = blockIdx.x;
    if (gb < 4096) {
        int idx = gb * 256 + threadIdx.x;
        const float* src; int off;
        if      (idx < 196608) { src = lq; off = idx; }
        else if (idx < 393216) { src = rq; off = idx - 196608; }
        else if (idx < 458752) { src = lo; off = idx - 393216; }
        else if (idx < 524288) { src = ro; off = idx - 458752; }
        else if (idx < 786432) { src = lh; off = idx - 524288; }
        else                   { src = rh; off = idx - 786432; }
        const float4 v = ((const float4*)src)[off];
        half4 h = { (_Float16)v.x, (_Float16)v.y, (_Float16)v.z, (_Float16)v.w };
        ((half4*)wdst)[idx] = h;
    } else {
        int idx = (gb - 4096) * 256 + threadIdx.x;   // MROWS*128 total
        const int c4 = idx & 127;
        const int t  = idx >> 7;
        const int n = t % NSEQ;
        const int b = t / NSEQ;
        const float* src;
        if (n < WIDTH_)            src = lp + n * 512;
        else if (n < WIDTH_ + S_)  src = inp + ((size_t)(b * S_ + n - WIDTH_)) * 512;
        else                       src = rp + (n - WIDTH_ - S_) * 512;
        const float4 v = *(const float4*)(src + c4 * 4);
        half4 h = { (_Float16)v.x, (_Float16)v.y, (_Float16)v.z, (_Float16)v.w };
        *(half4*)&padX[(size_t)t * 512 + c4 * 4] = h;
    }
}

extern "C" void kernel_launch(void* const* d_in, const int* in_sizes, int n_in,
                              void* d_out, int out_size, void* d_ws, size_t ws_size,
                              hipStream_t stream) {
    const float* inputs    = (const float*)d_in[0];
    const float* left_pad  = (const float*)d_in[1];
    const float* right_pad = (const float*)d_in[2];
    const float* l_Wqkv = (const float*)d_in[3];
    const float* l_bqkv = (const float*)d_in[4];
    const float* l_Wo   = (const float*)d_in[5];
    const float* l_bo   = (const float*)d_in[6];
    const float* r_Wqkv = (const float*)d_in[7];
    const float* r_bqkv = (const float*)d_in[8];
    const float* r_Wo   = (const float*)d_in[9];
    const float* r_bo   = (const float*)d_in[10];
    const float* lhw_W  = (const float*)d_in[11];
    const float* lhw_b  = (const float*)d_in[12];
    const float* rhw_W  = (const float*)d_in[13];
    const float* rhw_b  = (const float*)d_in[14];

    float* out = (float*)d_out;
    _Float16* h = (_Float16*)d_ws;

    // f16 arena offsets (f16 units)
    _Float16* padX16 = h;                    // 2,228,224
    _Float16* w16    = h + 2228224;          // 4,194,304
    _Float16* lqkv16 = w16;
    _Float16* rqkv16 = w16 + 786432;
    _Float16* lWo16  = w16 + 1572864;
    _Float16* rWo16  = w16 + 1835008;
    _Float16* lhw16  = w16 + 2097152;
    _Float16* rhw16  = w16 + 3145728;
    _Float16* qkv16  = h + 6422528;          // 13,369,344 (2 dirs)
    _Float16* att16  = h + 19791872;         // 4,456,448  (2 dirs)
    _Float16* x16a   = h + 24248320;         // 4,194,304  (2 dirs) ping
    _Float16* x16b   = h + 28442624;         // 4,194,304  (2 dirs) pong

    float* out_all  = out;            // all_layers [1,B,S,2D]
    float* out_last = out + OUTHALF;  // last       [B,S,2D]

    // fused weight cvt + pad concat
    prep<<<6272, 256, 0, stream>>>(l_Wqkv, r_Wqkv, l_Wo, r_Wo, lhw_W, rhw_W, w16,
                                   inputs, left_pad, right_pad, padX16);

    // QKV both dirs: [4352,512] x [1536,512]^T -> f16 [2][4352,1536]
    gemm_qkv<<<dim3(12, 34, 2), 256, 0, stream>>>(
        padX16, lqkv16, rqkv16, l_bqkv, r_bqkv, qkv16);

    // windowed attention both dirs -> att16 [2][4352,512]
    attn_win<<<dim3(272), 256, 0, stream>>>(qkv16, att16);

    // Wo + slice -> x16a (f16)
    gemm_wo<<<dim3(4, 68, 2), 256, 0, stream>>>(
        att16, lWo16, rWo16, l_bo, r_bo, x16a);

    // highway layer 1: x16a -> x16b
    gemm_hw<<<dim3(4, 32, 2), 512, 0, stream>>>(
        x16a, lhw16, rhw16, lhw_b, rhw_b, x16b, nullptr, nullptr);
    // highway layer 2: x16b -> out_last + out_all (f32)
    gemm_hw<<<dim3(4, 32, 2), 512, 0, stream>>>(
        x16b, lhw16 + 524288, rhw16 + 524288, lhw_b + 1024, rhw_b + 1024,
        nullptr, out_last, out_all);
}

// Round 8
// 186.162 us; speedup vs baseline: 1.0143x; 1.0143x over previous
//
#include <hip/hip_runtime.h>
#include <math.h>

#define B_ 8
#define S_ 512
#define D_ 512
#define WIDTH_ 16
#define NSEQ 544                 // S + 2*WIDTH
#define MROWS 4352               // B*NSEQ
#define MOUT 4096                // B*S
#define OUTHALF 4194304          // B*S*2D floats per output tensor

typedef _Float16 half8 __attribute__((ext_vector_type(8)));
typedef _Float16 half4 __attribute__((ext_vector_type(4)));
typedef float floatx4 __attribute__((ext_vector_type(4)));

// async global->LDS, 16B per lane, dest = wave-uniform base + lane*16
#define GLD16(g, l) __builtin_amdgcn_global_load_lds(                          \
    (const __attribute__((address_space(1))) void*)(g),                        \
    (__attribute__((address_space(3))) void*)(l), 16, 0, 0)

#define WAIT_VM(n)  asm volatile("s_waitcnt vmcnt(" #n ")" ::: "memory")
#define WAIT_LGKM0() asm volatile("s_waitcnt lgkmcnt(0)" ::: "memory")
#define BARRIER()                                                              \
    do {                                                                       \
        __builtin_amdgcn_s_barrier();                                          \
        asm volatile("" ::: "memory");                                         \
    } while (0)

__device__ __forceinline__ float sigmoidf_(float x) {
    return 1.f / (1.f + __expf(-x));
}

// XCD-contiguity swizzle: dispatch index d (round-robin over 8 XCDs) ->
// logical tile t = (d%8)*(nwg/8) + d/8 so each XCD gets a contiguous chunk.
// All grids here have nwg % 8 == 0 (bijective).
__device__ __forceinline__ void xcd_swz(const int nx, const int ny,
                                        int& bx, int& by, int& bz) {
    const int flat = blockIdx.x + nx * (blockIdx.y + ny * blockIdx.z);
    const int nwg  = nx * ny * 2;
    const int t2   = (flat & 7) * (nwg >> 3) + (flat >> 3);
    bz = t2 / (nx * ny);
    const int rem = t2 - bz * nx * ny;
    by = rem / nx;
    bx = rem - by * nx;
}

// ================= QKV GEMM: 128x128 tile, f16 out, dual-dir =================
// C16[z][m,n] = sum_k A[m,k]*B[z][n,k] + bias[z][n]
// grid (12, 34, 2), block 256.  Depth-2 counted-vmcnt pipeline.
// Epilogue: stage C-tile in LDS (reusing staging buffers) -> dwordx4 stores.
__global__ __launch_bounds__(256)
void gemm_qkv(const _Float16* __restrict__ A,
              const _Float16* __restrict__ B0, const _Float16* __restrict__ B1,
              const float* __restrict__ bias0, const float* __restrict__ bias1,
              _Float16* __restrict__ C16) {
    const int lda = 512, ldb = 512, ldc = 1536;
    __shared__ _Float16 SH[16384];   // 32 KB: As[2][4096] | Bs[2][4096]; CT reuse
    int bx, by, bz;
    xcd_swz(12, 34, bx, by, bz);
    const int t    = threadIdx.x;
    const int wave = t >> 6;
    const int lane = t & 63;
    const int bm = by * 128;
    const int bn = bx * 128;
    const int z  = bz;
    const _Float16* B = z ? B1 : B0;
    const float* bias = z ? bias1 : bias0;
    _Float16* C = C16 + (size_t)z * MROWS * 1536;
    const int wm = (wave & 1) * 64;
    const int wn = (wave >> 1) * 64;

    const int inst = wave * 2;
    const int r0 = inst * 16 + (lane >> 2);   // 16 rows per GLD16 inst
    const int kf = (lane & 3) * 8;

    const _Float16* Ag0 = A + (size_t)(bm + r0) * lda + kf;
    const _Float16* Ag1 = Ag0 + (size_t)16 * lda;
    const _Float16* Bg0 = B + (size_t)(bn + r0) * ldb + kf;
    const _Float16* Bg1 = Bg0 + (size_t)16 * ldb;
    const int so = inst * 512;                // f16 offset inside one buffer

    const int fr = lane & 15;
    const int fq = (lane >> 4) * 8;

    floatx4 acc[4][4] = {};

#define QKV_STAGE(bf_, koff_)                                                  \
    do {                                                                       \
        GLD16(Ag0 + (koff_), &SH[(bf_) * 4096 + so]);                          \
        GLD16(Ag1 + (koff_), &SH[(bf_) * 4096 + so + 512]);                    \
        GLD16(Bg0 + (koff_), &SH[8192 + (bf_) * 4096 + so]);                   \
        GLD16(Bg1 + (koff_), &SH[8192 + (bf_) * 4096 + so + 512]);             \
    } while (0)

    QKV_STAGE(0, 0);
    QKV_STAGE(1, 32);

#pragma unroll
    for (int tt = 0; tt < 16; tt++) {
        const int c = tt & 1;
        if (tt == 15) WAIT_VM(0);
        else          WAIT_VM(4);
        BARRIER();
        half8 af[4], bf[4];
#pragma unroll
        for (int s = 0; s < 4; s++) {
            af[s] = *(const half8*)&SH[c * 4096 + (wm + s * 16 + fr) * 32 + fq];
            bf[s] = *(const half8*)&SH[8192 + c * 4096 + (wn + s * 16 + fr) * 32 + fq];
        }
        WAIT_LGKM0();
        BARRIER();
        if (tt + 2 < 16) QKV_STAGE(c, (tt + 2) * 32);
#pragma unroll
        for (int i = 0; i < 4; i++)
#pragma unroll
            for (int j = 0; j < 4; j++)
                acc[i][j] = __builtin_amdgcn_mfma_f32_16x16x32_f16(
                    af[i], bf[j], acc[i][j], 0, 0, 0);
    }
#undef QKV_STAGE

    // ---- coalesced epilogue: acc -> LDS (f16, +bias) -> dwordx4 stores ----
    const int rq = (lane >> 4) * 4;
    const int cc = lane & 15;
#pragma unroll
    for (int i = 0; i < 4; i++) {
#pragma unroll
        for (int j = 0; j < 4; j++) {
            const int col = wn + j * 16 + cc;
            const float bv = bias[bn + col];
#pragma unroll
            for (int r = 0; r < 4; r++)
                SH[(wm + i * 16 + rq + r) * 128 + col] =
                    (_Float16)(acc[i][j][r] + bv);
        }
    }
    WAIT_LGKM0();
    BARRIER();
#pragma unroll
    for (int it = 0; it < 8; it++) {
        const int flat = it * 256 + t;
        const int row = flat >> 4;
        const int ch  = flat & 15;
        *(half8*)&C[(size_t)(bm + row) * ldc + bn + ch * 8] =
            *(const half8*)&SH[row * 128 + ch * 8];
    }
}

// ======== Wo GEMM: 64x128 tile, dual-dir, fused slice epilogue ========
// grid (4, 68, 2), block 256.  Depth-2 counted-vmcnt pipeline.
__global__ __launch_bounds__(256)
void gemm_wo(const _Float16* __restrict__ Aall,
             const _Float16* __restrict__ B0, const _Float16* __restrict__ B1,
             const float* __restrict__ bias0, const float* __restrict__ bias1,
             _Float16* __restrict__ x16base) { // +z*MOUT*512
    const int lda = 512, ldb = 512;
    __shared__ _Float16 As[2][64 * 32];     // 8 KB
    __shared__ _Float16 Bs[2][128 * 32];    // 16 KB
    int bx, by, bz;
    xcd_swz(4, 68, bx, by, bz);
    const int t    = threadIdx.x;
    const int wave = t >> 6;
    const int lane = t & 63;
    const int bm = by * 64;
    const int bn = bx * 128;
    const int z  = bz;
    const _Float16* A = Aall + (size_t)z * MROWS * 512;
    const _Float16* B = z ? B1 : B0;
    const float* bias = z ? bias1 : bias0;
    _Float16* x16 = x16base + (size_t)z * MOUT * 512;

    const int wm = (wave & 1) * 32;
    const int wn = (wave >> 1) * 64;

    const int rA = wave * 16 + (lane >> 2);
    const int rB = wave * 32 + (lane >> 2);
    const int kf = (lane & 3) * 8;

    const _Float16* Ag0 = A + (size_t)(bm + rA) * lda + kf;
    const _Float16* Bg0 = B + (size_t)(bn + rB) * ldb + kf;
    const _Float16* Bg1 = Bg0 + (size_t)16 * ldb;
    const int soA = wave * 512;
    const int soB = wave * 1024;

    const int fr = lane & 15;
    const int fq = (lane >> 4) * 8;

    floatx4 acc[2][4] = {};

#define WO_STAGE(bf_, koff_)                                                   \
    do {                                                                       \
        GLD16(Ag0 + (koff_), &As[bf_][soA]);                                   \
        GLD16(Bg0 + (koff_), &Bs[bf_][soB]);                                   \
        GLD16(Bg1 + (koff_), &Bs[bf_][soB + 512]);                             \
    } while (0)

    WO_STAGE(0, 0);
    WO_STAGE(1, 32);

#pragma unroll
    for (int tt = 0; tt < 16; tt++) {
        const int c = tt & 1;
        if (tt == 15) WAIT_VM(0);
        else          WAIT_VM(3);
        BARRIER();
        half8 af[2], bf[4];
#pragma unroll
        for (int s = 0; s < 2; s++)
            af[s] = *(const half8*)&As[c][(wm + s * 16 + fr) * 32 + fq];
#pragma unroll
        for (int s = 0; s < 4; s++)
            bf[s] = *(const half8*)&Bs[c][(wn + s * 16 + fr) * 32 + fq];
        WAIT_LGKM0();
        BARRIER();
        if (tt + 2 < 16) WO_STAGE(c, (tt + 2) * 32);
#pragma unroll
        for (int i = 0; i < 2; i++)
#pragma unroll
            for (int j = 0; j < 4; j++)
                acc[i][j] = __builtin_amdgcn_mfma_f32_16x16x32_f16(
                    af[i], bf[j], acc[i][j], 0, 0, 0);
    }
#undef WO_STAGE

    const int rq = (lane >> 4) * 4;
    const int cc = lane & 15;
#pragma unroll
    for (int i = 0; i < 2; i++) {
        const int rbase = bm + wm + i * 16 + rq;
#pragma unroll
        for (int r = 0; r < 4; r++) {
            const int row = rbase + r;
            const int b = row / NSEQ;
            const int s = row - b * NSEQ;
            if (s < WIDTH_ || s >= WIDTH_ + S_) continue;
            const int m = b * S_ + s - WIDTH_;
#pragma unroll
            for (int j = 0; j < 4; j++) {
                const int col = bn + wn + j * 16 + cc;
                x16[(size_t)m * 512 + col] = (_Float16)(acc[i][j][r] + bias[col]);
            }
        }
    }
}

// ==== Highway GEMM: 128x64 tile, dual-N (nonlin+gate), fused combine ====
// grid (8, 32, 2), block 256.  Depth-2 counted-vmcnt.
// Layer-1 epilogue stages f16 output in LDS for coalesced dwordx4 stores.
__global__ __launch_bounds__(256)
void gemm_hw(const _Float16* __restrict__ x16inbase,
             const _Float16* __restrict__ W0, const _Float16* __restrict__ W1,
             const float* __restrict__ b0, const float* __restrict__ b1,
             _Float16* __restrict__ x16outbase,   // null on last layer
             float* __restrict__ outlastbase,     // last layer only
             float* __restrict__ outallbase) {    // last layer only
    const int lda = 512, ldb = 512;
    __shared__ _Float16 SA[8192];          // As[2][4096] = 16 KB; CT reuse
    __shared__ _Float16 Bn[2][64 * 32];    // 8 KB
    __shared__ _Float16 Bg[2][64 * 32];    // 8 KB
    int bx, by, bz;
    xcd_swz(8, 32, bx, by, bz);
    const int t    = threadIdx.x;
    const int wave = t >> 6;
    const int lane = t & 63;
    const int bm = by * 128;
    const int bn = bx * 64;     // col block within [0,512)
    const int z  = bz;
    const _Float16* A = x16inbase + (size_t)z * MOUT * 512;
    const _Float16* W = z ? W1 : W0;
    const float* bias = z ? b1 : b0;
    _Float16* x16out = x16outbase ? x16outbase + (size_t)z * MOUT * 512 : nullptr;

    const int wm = (wave & 1) * 64;
    const int wn = (wave >> 1) * 32;

    const int rA = wave * 32 + (lane >> 2);
    const int rB = wave * 16 + (lane >> 2);
    const int kf = (lane & 3) * 8;

    const _Float16* Ag0 = A + (size_t)(bm + rA) * lda + kf;
    const _Float16* Ag1 = Ag0 + (size_t)16 * lda;
    const _Float16* Bn0 = W + (size_t)(bn + rB) * ldb + kf;
    const _Float16* Bg0 = W + (size_t)(512 + bn + rB) * ldb + kf;
    const int soA = wave * 1024;
    const int soB = wave * 512;

    const int fr = lane & 15;
    const int fq = (lane >> 4) * 8;

    floatx4 accn[4][2] = {};
    floatx4 accg[4][2] = {};

#define HW_STAGE(bf_, koff_)                                                   \
    do {                                                                       \
        GLD16(Ag0 + (koff_), &SA[(bf_) * 4096 + soA]);                         \
        GLD16(Ag1 + (koff_), &SA[(bf_) * 4096 + soA + 512]);                   \
        GLD16(Bn0 + (koff_), &Bn[bf_][soB]);                                   \
        GLD16(Bg0 + (koff_), &Bg[bf_][soB]);                                   \
    } while (0)

    HW_STAGE(0, 0);
    HW_STAGE(1, 32);

#pragma unroll
    for (int tt = 0; tt < 16; tt++) {
        const int c = tt & 1;
        if (tt == 15) WAIT_VM(0);
        else          WAIT_VM(4);
        BARRIER();
        half8 af[4], bnf[2], bgf[2];
#pragma unroll
        for (int s = 0; s < 4; s++)
            af[s] = *(const half8*)&SA[c * 4096 + (wm + s * 16 + fr) * 32 + fq];
#pragma unroll
        for (int s = 0; s < 2; s++) {
            bnf[s] = *(const half8*)&Bn[c][(wn + s * 16 + fr) * 32 + fq];
            bgf[s] = *(const half8*)&Bg[c][(wn + s * 16 + fr) * 32 + fq];
        }
        WAIT_LGKM0();
        BARRIER();
        if (tt + 2 < 16) HW_STAGE(c, (tt + 2) * 32);
#pragma unroll
        for (int i = 0; i < 4; i++)
#pragma unroll
            for (int j = 0; j < 2; j++) {
                accn[i][j] = __builtin_amdgcn_mfma_f32_16x16x32_f16(
                    af[i], bnf[j], accn[i][j], 0, 0, 0);
                accg[i][j] = __builtin_amdgcn_mfma_f32_16x16x32_f16(
                    af[i], bgf[j], accg[i][j], 0, 0, 0);
            }
    }
#undef HW_STAGE

    const int rq = (lane >> 4) * 4;
    const int cc = lane & 15;
    if (x16out) {
        // combine -> LDS f16 tile [128][64] -> coalesced stores
#pragma unroll
        for (int i = 0; i < 4; i++) {
#pragma unroll
            for (int j = 0; j < 2; j++) {
                const int col = wn + j * 16 + cc;
                const float bnl = bias[bn + col];
                const float bgt = bias[512 + bn + col];
#pragma unroll
                for (int r = 0; r < 4; r++) {
                    const int row = wm + i * 16 + rq + r;
                    const float nl = fmaxf(accn[i][j][r] + bnl, 0.f);
                    const float g  = sigmoidf_(accg[i][j][r] + bgt);
                    const float xo = (float)A[(size_t)(bm + row) * 512 + bn + col];
                    SA[row * 64 + col] = (_Float16)(g * xo + (1.f - g) * nl);
                }
            }
        }
        WAIT_LGKM0();
        BARRIER();
#pragma unroll
        for (int it = 0; it < 4; it++) {
            const int flat = it * 256 + t;
            const int row = flat >> 3;
            const int ch  = flat & 7;
            *(half8*)&x16out[(size_t)(bm + row) * 512 + bn + ch * 8] =
                *(const half8*)&SA[row * 64 + ch * 8];
        }
    } else {
        float* outlast = outlastbase + z * 512;
        float* outall  = outallbase  + z * 512;
#pragma unroll
        for (int i = 0; i < 4; i++) {
            const int rbase = bm + wm + i * 16 + rq;
#pragma unroll
            for (int j = 0; j < 2; j++) {
                const int col = bn + wn + j * 16 + cc;
                const float bnl = bias[col];
                const float bgt = bias[512 + col];
#pragma unroll
                for (int r = 0; r < 4; r++) {
                    const int row = rbase + r;
                    const float nl = fmaxf(accn[i][j][r] + bnl, 0.f);
                    const float g  = sigmoidf_(accg[i][j][r] + bgt);
                    const float xo = (float)A[(size_t)row * 512 + col];
                    const float v  = g * xo + (1.f - g) * nl;
                    outlast[(size_t)row * 1024 + col] = v;
                    outall[(size_t)row * 1024 + col] = v;
                }
            }
        }
    }
}

// ---------- windowed attention, dual-dir, TI=4 query-sliding window ----------
// Thread = (dir, b, head, 4 consecutive queries).  Loads 21 K/V rows instead
// of 72 (3.4x less L2/L3 traffic).  Window condition is compile-time after
// unroll: query t uses jj in [t, t+17] for BOTH directions.
// grid 544 blocks x 256 thr; wave = 64 heads of one (dir,b,query-group).
__global__ __launch_bounds__(256)
void attn_win(const _Float16* __restrict__ qkvall, _Float16* __restrict__ attall) {
    const int sb  = (blockIdx.x & 7) * 68 + (blockIdx.x >> 3);   // XCD swizzle
    const int wid = threadIdx.x >> 6;
    const int h   = threadIdx.x & 63;
    const int wflat = sb * 4 + wid;          // 0..2175
    const int ig  = wflat % 136;
    const int db  = wflat / 136;             // 0..15
    const int b   = db & 7;
    const int dir = db >> 3;
    const int i0  = ig * 4;
    const int dlo = dir ? 0 : -17;
    const _Float16* qkv = qkvall + (size_t)dir * MROWS * 1536;
    _Float16* att = attall + (size_t)dir * MROWS * 512;
    const size_t rowb = (size_t)b * NSEQ;
    const float scale = 0.35355339059327373f;  // 1/sqrt(8)

    float q[4][8];
#pragma unroll
    for (int tq = 0; tq < 4; tq++) {
        const half8 q8 = *(const half8*)(qkv + (rowb + i0 + tq) * 1536 + h * 8);
#pragma unroll
        for (int d = 0; d < 8; d++) q[tq][d] = (float)q8[d];
    }

    float o[4][8] = {};
    float sum[4] = {};
    const int j0 = i0 + dlo;

#pragma unroll
    for (int jj = 0; jj < 21; jj++) {
        const int j = j0 + jj;
        if (j < 0 || j > NSEQ - 1) continue;   // wave-uniform branch
        const size_t jbase = (rowb + j) * 1536 + h * 8;
        const half8 k8 = *(const half8*)(qkv + jbase + 512);
        const half8 v8 = *(const half8*)(qkv + jbase + 1024);
        float kv[8], vv[8];
#pragma unroll
        for (int d = 0; d < 8; d++) { kv[d] = (float)k8[d]; vv[d] = (float)v8[d]; }
#pragma unroll
        for (int tq = 0; tq < 4; tq++) {
            if (jj < tq || jj > tq + 17) continue;  // compile-time prune
            float d = 0.f;
#pragma unroll
            for (int dd = 0; dd < 8; dd++) d = fmaf(q[tq][dd], kv[dd], d);
            const float p = __expf(d * scale);   // shift-free softmax (s is O(1))
            sum[tq] += p;
#pragma unroll
            for (int dd = 0; dd < 8; dd++) o[tq][dd] = fmaf(p, vv[dd], o[tq][dd]);
        }
    }

#pragma unroll
    for (int tq = 0; tq < 4; tq++) {
        const float inv = 1.f / sum[tq];
        half8 o16;
#pragma unroll
        for (int d = 0; d < 8; d++) o16[d] = (_Float16)(o[tq][d] * inv);
        *(half8*)&att[(rowb + i0 + tq) * 512 + h * 8] = o16;
    }
}

// ====== prep: fused weight convert (6 tensors) + pad-concat to f16 ======
__global__ void prep(const float* __restrict__ lq, const float* __restrict__ rq,
                     const float* __restrict__ lo, const float* __restrict__ ro,
                     const float* __restrict__ lh, const float* __restrict__ rh,
                     _Float16* __restrict__ wdst,
                     const float* __restrict__ inp,
                     const float* __restrict__ lp,
                     const float* __restrict__ rp,
                     _Float16* __restrict__ padX) {
    const int gb = blockIdx.x;
    if (gb < 4096) {
        int idx = gb * 256 + threadIdx.x;
        const float* src; int off;
        if      (idx < 196608) { src = lq; off = idx; }
        else if (idx < 393216) { src = rq; off = idx - 196608; }
        else if (idx < 458752) { src = lo; off = idx - 393216; }
        else if (idx < 524288) { src = ro; off = idx - 458752; }
        else if (idx < 786432) { src = lh; off = idx - 524288; }
        else                   { src = rh; off = idx - 786432; }
        const float4 v = ((const float4*)src)[off];
        half4 h = { (_Float16)v.x, (_Float16)v.y, (_Float16)v.z, (_Float16)v.w };
        ((half4*)wdst)[idx] = h;
    } else {
        int idx = (gb - 4096) * 256 + threadIdx.x;   // MROWS*128 total
        const int c4 = idx & 127;
        const int t  = idx >> 7;
        const int n = t % NSEQ;
        const int b = t / NSEQ;
        const float* src;
        if (n < WIDTH_)            src = lp + n * 512;
        else if (n < WIDTH_ + S_)  src = inp + ((size_t)(b * S_ + n - WIDTH_)) * 512;
        else                       src = rp + (n - WIDTH_ - S_) * 512;
        const float4 v = *(const float4*)(src + c4 * 4);
        half4 h = { (_Float16)v.x, (_Float16)v.y, (_Float16)v.z, (_Float16)v.w };
        *(half4*)&padX[(size_t)t * 512 + c4 * 4] = h;
    }
}

extern "C" void kernel_launch(void* const* d_in, const int* in_sizes, int n_in,
                              void* d_out, int out_size, void* d_ws, size_t ws_size,
                              hipStream_t stream) {
    const float* inputs    = (const float*)d_in[0];
    const float* left_pad  = (const float*)d_in[1];
    const float* right_pad = (const float*)d_in[2];
    const float* l_Wqkv = (const float*)d_in[3];
    const float* l_bqkv = (const float*)d_in[4];
    const float* l_Wo   = (const float*)d_in[5];
    const float* l_bo   = (const float*)d_in[6];
    const float* r_Wqkv = (const float*)d_in[7];
    const float* r_bqkv = (const float*)d_in[8];
    const float* r_Wo   = (const float*)d_in[9];
    const float* r_bo   = (const float*)d_in[10];
    const float* lhw_W  = (const float*)d_in[11];
    const float* lhw_b  = (const float*)d_in[12];
    const float* rhw_W  = (const float*)d_in[13];
    const float* rhw_b  = (const float*)d_in[14];

    float* out = (float*)d_out;
    _Float16* h = (_Float16*)d_ws;

    // f16 arena offsets (f16 units)
    _Float16* padX16 = h;                    // 2,228,224
    _Float16* w16    = h + 2228224;          // 4,194,304
    _Float16* lqkv16 = w16;
    _Float16* rqkv16 = w16 + 786432;
    _Float16* lWo16  = w16 + 1572864;
    _Float16* rWo16  = w16 + 1835008;
    _Float16* lhw16  = w16 + 2097152;
    _Float16* rhw16  = w16 + 3145728;
    _Float16* qkv16  = h + 6422528;          // 13,369,344 (2 dirs)
    _Float16* att16  = h + 19791872;         // 4,456,448  (2 dirs)
    _Float16* x16a   = h + 24248320;         // 4,194,304  (2 dirs) ping
    _Float16* x16b   = h + 28442624;         // 4,194,304  (2 dirs) pong

    float* out_all  = out;            // all_layers [1,B,S,2D]
    float* out_last = out + OUTHALF;  // last       [B,S,2D]

    // fused weight cvt + pad concat
    prep<<<6272, 256, 0, stream>>>(l_Wqkv, r_Wqkv, l_Wo, r_Wo, lhw_W, rhw_W, w16,
                                   inputs, left_pad, right_pad, padX16);

    // QKV both dirs: [4352,512] x [1536,512]^T -> f16 [2][4352,1536]
    gemm_qkv<<<dim3(12, 34, 2), 256, 0, stream>>>(
        padX16, lqkv16, rqkv16, l_bqkv, r_bqkv, qkv16);

    // windowed attention both dirs -> att16 [2][4352,512]
    attn_win<<<dim3(544), 256, 0, stream>>>(qkv16, att16);

    // Wo + slice -> x16a (f16)
    gemm_wo<<<dim3(4, 68, 2), 256, 0, stream>>>(
        att16, lWo16, rWo16, l_bo, r_bo, x16a);

    // highway layer 1: x16a -> x16b
    gemm_hw<<<dim3(8, 32, 2), 256, 0, stream>>>(
        x16a, lhw16, rhw16, lhw_b, rhw_b, x16b, nullptr, nullptr);
    // highway layer 2: x16b -> out_last + out_all (f32)
    gemm_hw<<<dim3(8, 32, 2), 256, 0, stream>>>(
        x16b, lhw16 + 524288, rhw16 + 524288, lhw_b + 1024, rhw_b + 1024,
        nullptr, out_last, out_all);
}

// Round 9
// 183.702 us; speedup vs baseline: 1.0279x; 1.0134x over previous
//
#include <hip/hip_runtime.h>
#include <math.h>

#define B_ 8
#define S_ 512
#define D_ 512
#define WIDTH_ 16
#define NSEQ 544                 // S + 2*WIDTH
#define MROWS 4352               // B*NSEQ
#define MOUT 4096                // B*S
#define OUTHALF 4194304          // B*S*2D floats per output tensor

typedef _Float16 half8 __attribute__((ext_vector_type(8)));
typedef _Float16 half4 __attribute__((ext_vector_type(4)));
typedef float floatx4 __attribute__((ext_vector_type(4)));

// async global->LDS, 16B per lane, dest = wave-uniform base + lane*16
#define GLD16(g, l) __builtin_amdgcn_global_load_lds(                          \
    (const __attribute__((address_space(1))) void*)(g),                        \
    (__attribute__((address_space(3))) void*)(l), 16, 0, 0)

#define WAIT_VM(n)  asm volatile("s_waitcnt vmcnt(" #n ")" ::: "memory")
#define WAIT_LGKM0() asm volatile("s_waitcnt lgkmcnt(0)" ::: "memory")
#define BARRIER()                                                              \
    do {                                                                       \
        __builtin_amdgcn_s_barrier();                                          \
        asm volatile("" ::: "memory");                                         \
    } while (0)

__device__ __forceinline__ float sigmoidf_(float x) {
    return 1.f / (1.f + __expf(-x));
}

// XCD-contiguity swizzle: dispatch index d (round-robin over 8 XCDs) ->
// logical tile t = (d%8)*(nwg/8) + d/8 so each XCD gets a contiguous chunk.
// All grids here have nwg % 8 == 0 (bijective).
__device__ __forceinline__ void xcd_swz(const int nx, const int ny,
                                        int& bx, int& by, int& bz) {
    const int flat = blockIdx.x + nx * (blockIdx.y + ny * blockIdx.z);
    const int nwg  = nx * ny * 2;
    const int t2   = (flat & 7) * (nwg >> 3) + (flat >> 3);
    bz = t2 / (nx * ny);
    const int rem = t2 - bz * nx * ny;
    by = rem / nx;
    bx = rem - by * nx;
}

// ================= QKV GEMM: 128x128 tile, f16 out, dual-dir =================
// C16[z][m,n] = sum_k A[m,k]*B[z][n,k] + bias[z][n]
// grid (12, 34, 2), block 256.  Depth-2 counted-vmcnt pipeline (R3-proven).
// Epilogue: stage C-tile in LDS (reusing staging buffers) -> half8 stores.
__global__ __launch_bounds__(256)
void gemm_qkv(const _Float16* __restrict__ A,
              const _Float16* __restrict__ B0, const _Float16* __restrict__ B1,
              const float* __restrict__ bias0, const float* __restrict__ bias1,
              _Float16* __restrict__ C16) {
    const int lda = 512, ldb = 512, ldc = 1536;
    __shared__ _Float16 SH[16384];   // 32 KB: As[2][4096] | Bs[2][4096]; CT reuse
    int bx, by, bz;
    xcd_swz(12, 34, bx, by, bz);
    const int t    = threadIdx.x;
    const int wave = t >> 6;
    const int lane = t & 63;
    const int bm = by * 128;
    const int bn = bx * 128;
    const int z  = bz;
    const _Float16* B = z ? B1 : B0;
    const float* bias = z ? bias1 : bias0;
    _Float16* C = C16 + (size_t)z * MROWS * 1536;
    const int wm = (wave & 1) * 64;
    const int wn = (wave >> 1) * 64;

    const int inst = wave * 2;
    const int r0 = inst * 16 + (lane >> 2);   // 16 rows per GLD16 inst
    const int kf = (lane & 3) * 8;

    const _Float16* Ag0 = A + (size_t)(bm + r0) * lda + kf;
    const _Float16* Ag1 = Ag0 + (size_t)16 * lda;
    const _Float16* Bg0 = B + (size_t)(bn + r0) * ldb + kf;
    const _Float16* Bg1 = Bg0 + (size_t)16 * ldb;
    const int so = inst * 512;                // f16 offset inside one buffer

    const int fr = lane & 15;
    const int fq = (lane >> 4) * 8;

    floatx4 acc[4][4] = {};

#define QKV_STAGE(bf_, koff_)                                                  \
    do {                                                                       \
        GLD16(Ag0 + (koff_), &SH[(bf_) * 4096 + so]);                          \
        GLD16(Ag1 + (koff_), &SH[(bf_) * 4096 + so + 512]);                    \
        GLD16(Bg0 + (koff_), &SH[8192 + (bf_) * 4096 + so]);                   \
        GLD16(Bg1 + (koff_), &SH[8192 + (bf_) * 4096 + so + 512]);             \
    } while (0)

    QKV_STAGE(0, 0);
    QKV_STAGE(1, 32);

#pragma unroll
    for (int tt = 0; tt < 16; tt++) {
        const int c = tt & 1;
        if (tt == 15) WAIT_VM(0);
        else          WAIT_VM(4);
        BARRIER();
        half8 af[4], bf[4];
#pragma unroll
        for (int s = 0; s < 4; s++) {
            af[s] = *(const half8*)&SH[c * 4096 + (wm + s * 16 + fr) * 32 + fq];
            bf[s] = *(const half8*)&SH[8192 + c * 4096 + (wn + s * 16 + fr) * 32 + fq];
        }
        WAIT_LGKM0();
        BARRIER();
        if (tt + 2 < 16) QKV_STAGE(c, (tt + 2) * 32);
#pragma unroll
        for (int i = 0; i < 4; i++)
#pragma unroll
            for (int j = 0; j < 4; j++)
                acc[i][j] = __builtin_amdgcn_mfma_f32_16x16x32_f16(
                    af[i], bf[j], acc[i][j], 0, 0, 0);
    }
#undef QKV_STAGE

    // ---- coalesced epilogue: acc -> LDS (f16, +bias) -> half8 stores ----
    const int rq = (lane >> 4) * 4;
    const int cc = lane & 15;
#pragma unroll
    for (int i = 0; i < 4; i++) {
#pragma unroll
        for (int j = 0; j < 4; j++) {
            const int col = wn + j * 16 + cc;
            const float bv = bias[bn + col];
#pragma unroll
            for (int r = 0; r < 4; r++)
                SH[(wm + i * 16 + rq + r) * 128 + col] =
                    (_Float16)(acc[i][j][r] + bv);
        }
    }
    WAIT_LGKM0();
    BARRIER();
#pragma unroll
    for (int it = 0; it < 8; it++) {
        const int flat = it * 256 + t;
        const int row = flat >> 4;
        const int ch  = flat & 15;
        *(half8*)&C[(size_t)(bm + row) * ldc + bn + ch * 8] =
            *(const half8*)&SH[row * 128 + ch * 8];
    }
}

// ======== Wo GEMM: 64x128 tile, dual-dir, sliced-row A addressing ========
// grid (4, 64, 2) = 512 blocks = exactly 2/CU (no 32-block tail).
// Output rows are x-space [0,4096) directly; the A rows are addressed through
// the slice map arow = b*544 + 16 + (bm%512) + r -- a 64-row tile never
// crosses a batch boundary (64 | 512), so staging is unchanged.  Epilogue
// needs no slice test (every row valid).  Dead att pad rows never read.
__global__ __launch_bounds__(256)
void gemm_wo(const _Float16* __restrict__ Aall,
             const _Float16* __restrict__ B0, const _Float16* __restrict__ B1,
             const float* __restrict__ bias0, const float* __restrict__ bias1,
             _Float16* __restrict__ x16base) { // +z*MOUT*512
    const int lda = 512, ldb = 512;
    __shared__ _Float16 As[2][64 * 32];     // 8 KB
    __shared__ _Float16 Bs[2][128 * 32];    // 16 KB
    int bx, by, bz;
    xcd_swz(4, 64, bx, by, bz);
    const int t    = threadIdx.x;
    const int wave = t >> 6;
    const int lane = t & 63;
    const int bm = by * 64;                 // x-space row base
    const int bn = bx * 128;
    const int z  = bz;
    const _Float16* A = Aall + (size_t)z * MROWS * 512;
    const _Float16* B = z ? B1 : B0;
    const float* bias = z ? bias1 : bias0;
    _Float16* x16 = x16base + (size_t)z * MOUT * 512;

    const int bb   = bm >> 9;               // batch index
    const int arow = bb * NSEQ + WIDTH_ + (bm & 511);   // att-space row base

    const int wm = (wave & 1) * 32;
    const int wn = (wave >> 1) * 64;

    const int rA = wave * 16 + (lane >> 2);
    const int rB = wave * 32 + (lane >> 2);
    const int kf = (lane & 3) * 8;

    const _Float16* Ag0 = A + (size_t)(arow + rA) * lda + kf;
    const _Float16* Bg0 = B + (size_t)(bn + rB) * ldb + kf;
    const _Float16* Bg1 = Bg0 + (size_t)16 * ldb;
    const int soA = wave * 512;
    const int soB = wave * 1024;

    const int fr = lane & 15;
    const int fq = (lane >> 4) * 8;

    floatx4 acc[2][4] = {};

#define WO_STAGE(bf_, koff_)                                                   \
    do {                                                                       \
        GLD16(Ag0 + (koff_), &As[bf_][soA]);                                   \
        GLD16(Bg0 + (koff_), &Bs[bf_][soB]);                                   \
        GLD16(Bg1 + (koff_), &Bs[bf_][soB + 512]);                             \
    } while (0)

    WO_STAGE(0, 0);
    WO_STAGE(1, 32);

#pragma unroll
    for (int tt = 0; tt < 16; tt++) {
        const int c = tt & 1;
        if (tt == 15) WAIT_VM(0);
        else          WAIT_VM(3);
        BARRIER();
        half8 af[2], bf[4];
#pragma unroll
        for (int s = 0; s < 2; s++)
            af[s] = *(const half8*)&As[c][(wm + s * 16 + fr) * 32 + fq];
#pragma unroll
        for (int s = 0; s < 4; s++)
            bf[s] = *(const half8*)&Bs[c][(wn + s * 16 + fr) * 32 + fq];
        WAIT_LGKM0();
        BARRIER();
        if (tt + 2 < 16) WO_STAGE(c, (tt + 2) * 32);
#pragma unroll
        for (int i = 0; i < 2; i++)
#pragma unroll
            for (int j = 0; j < 4; j++)
                acc[i][j] = __builtin_amdgcn_mfma_f32_16x16x32_f16(
                    af[i], bf[j], acc[i][j], 0, 0, 0);
    }
#undef WO_STAGE

    const int rq = (lane >> 4) * 4;
    const int cc = lane & 15;
#pragma unroll
    for (int i = 0; i < 2; i++) {
        const int rbase = bm + wm + i * 16 + rq;
#pragma unroll
        for (int r = 0; r < 4; r++) {
            const int m = rbase + r;        // always a valid x row
#pragma unroll
            for (int j = 0; j < 4; j++) {
                const int col = bn + wn + j * 16 + cc;
                x16[(size_t)m * 512 + col] = (_Float16)(acc[i][j][r] + bias[col]);
            }
        }
    }
}

// ==== Highway GEMM: 128x64 tile, dual-N (nonlin+gate), fused combine ====
// grid (8, 32, 2), block 256.  R3-proven (unchanged from R8).
__global__ __launch_bounds__(256)
void gemm_hw(const _Float16* __restrict__ x16inbase,
             const _Float16* __restrict__ W0, const _Float16* __restrict__ W1,
             const float* __restrict__ b0, const float* __restrict__ b1,
             _Float16* __restrict__ x16outbase,   // null on last layer
             float* __restrict__ outlastbase,     // last layer only
             float* __restrict__ outallbase) {    // last layer only
    const int lda = 512, ldb = 512;
    __shared__ _Float16 SA[8192];          // As[2][4096] = 16 KB; CT reuse
    __shared__ _Float16 Bn[2][64 * 32];    // 8 KB
    __shared__ _Float16 Bg[2][64 * 32];    // 8 KB
    int bx, by, bz;
    xcd_swz(8, 32, bx, by, bz);
    const int t    = threadIdx.x;
    const int wave = t >> 6;
    const int lane = t & 63;
    const int bm = by * 128;
    const int bn = bx * 64;     // col block within [0,512)
    const int z  = bz;
    const _Float16* A = x16inbase + (size_t)z * MOUT * 512;
    const _Float16* W = z ? W1 : W0;
    const float* bias = z ? b1 : b0;
    _Float16* x16out = x16outbase ? x16outbase + (size_t)z * MOUT * 512 : nullptr;

    const int wm = (wave & 1) * 64;
    const int wn = (wave >> 1) * 32;

    const int rA = wave * 32 + (lane >> 2);
    const int rB = wave * 16 + (lane >> 2);
    const int kf = (lane & 3) * 8;

    const _Float16* Ag0 = A + (size_t)(bm + rA) * lda + kf;
    const _Float16* Ag1 = Ag0 + (size_t)16 * lda;
    const _Float16* Bn0 = W + (size_t)(bn + rB) * ldb + kf;
    const _Float16* Bg0 = W + (size_t)(512 + bn + rB) * ldb + kf;
    const int soA = wave * 1024;
    const int soB = wave * 512;

    const int fr = lane & 15;
    const int fq = (lane >> 4) * 8;

    floatx4 accn[4][2] = {};
    floatx4 accg[4][2] = {};

#define HW_STAGE(bf_, koff_)                                                   \
    do {                                                                       \
        GLD16(Ag0 + (koff_), &SA[(bf_) * 4096 + soA]);                         \
        GLD16(Ag1 + (koff_), &SA[(bf_) * 4096 + soA + 512]);                   \
        GLD16(Bn0 + (koff_), &Bn[bf_][soB]);                                   \
        GLD16(Bg0 + (koff_), &Bg[bf_][soB]);                                   \
    } while (0)

    HW_STAGE(0, 0);
    HW_STAGE(1, 32);

#pragma unroll
    for (int tt = 0; tt < 16; tt++) {
        const int c = tt & 1;
        if (tt == 15) WAIT_VM(0);
        else          WAIT_VM(4);
        BARRIER();
        half8 af[4], bnf[2], bgf[2];
#pragma unroll
        for (int s = 0; s < 4; s++)
            af[s] = *(const half8*)&SA[c * 4096 + (wm + s * 16 + fr) * 32 + fq];
#pragma unroll
        for (int s = 0; s < 2; s++) {
            bnf[s] = *(const half8*)&Bn[c][(wn + s * 16 + fr) * 32 + fq];
            bgf[s] = *(const half8*)&Bg[c][(wn + s * 16 + fr) * 32 + fq];
        }
        WAIT_LGKM0();
        BARRIER();
        if (tt + 2 < 16) HW_STAGE(c, (tt + 2) * 32);
#pragma unroll
        for (int i = 0; i < 4; i++)
#pragma unroll
            for (int j = 0; j < 2; j++) {
                accn[i][j] = __builtin_amdgcn_mfma_f32_16x16x32_f16(
                    af[i], bnf[j], accn[i][j], 0, 0, 0);
                accg[i][j] = __builtin_amdgcn_mfma_f32_16x16x32_f16(
                    af[i], bgf[j], accg[i][j], 0, 0, 0);
            }
    }
#undef HW_STAGE

    const int rq = (lane >> 4) * 4;
    const int cc = lane & 15;
    if (x16out) {
        // combine -> LDS f16 tile [128][64] -> coalesced stores
#pragma unroll
        for (int i = 0; i < 4; i++) {
#pragma unroll
            for (int j = 0; j < 2; j++) {
                const int col = wn + j * 16 + cc;
                const float bnl = bias[bn + col];
                const float bgt = bias[512 + bn + col];
#pragma unroll
                for (int r = 0; r < 4; r++) {
                    const int row = wm + i * 16 + rq + r;
                    const float nl = fmaxf(accn[i][j][r] + bnl, 0.f);
                    const float g  = sigmoidf_(accg[i][j][r] + bgt);
                    const float xo = (float)A[(size_t)(bm + row) * 512 + bn + col];
                    SA[row * 64 + col] = (_Float16)(g * xo + (1.f - g) * nl);
                }
            }
        }
        WAIT_LGKM0();
        BARRIER();
#pragma unroll
        for (int it = 0; it < 4; it++) {
            const int flat = it * 256 + t;
            const int row = flat >> 3;
            const int ch  = flat & 7;
            *(half8*)&x16out[(size_t)(bm + row) * 512 + bn + ch * 8] =
                *(const half8*)&SA[row * 64 + ch * 8];
        }
    } else {
        float* outlast = outlastbase + z * 512;
        float* outall  = outallbase  + z * 512;
#pragma unroll
        for (int i = 0; i < 4; i++) {
            const int rbase = bm + wm + i * 16 + rq;
#pragma unroll
            for (int j = 0; j < 2; j++) {
                const int col = bn + wn + j * 16 + cc;
                const float bnl = bias[col];
                const float bgt = bias[512 + col];
#pragma unroll
                for (int r = 0; r < 4; r++) {
                    const int row = rbase + r;
                    const float nl = fmaxf(accn[i][j][r] + bnl, 0.f);
                    const float g  = sigmoidf_(accg[i][j][r] + bgt);
                    const float xo = (float)A[(size_t)row * 512 + col];
                    const float v  = g * xo + (1.f - g) * nl;
                    outlast[(size_t)row * 1024 + col] = v;
                    outall[(size_t)row * 1024 + col] = v;
                }
            }
        }
    }
}

// ---------- windowed attention, dual-dir, TI=4, LIVE ROWS ONLY ----------
// Only rows [16,528) per batch are ever consumed downstream (wo's output row
// m depends solely on att row m, and pad rows are sliced away) -> skip the
// 32 dead rows/batch.  i0 = (group+4)*4 in [16,528).  grid 512 x 256 =
// exactly 2 blocks/CU, no scheduling tail.  K/V window reads still cover all
// 544 rows; masking identical to R3/R8.
__global__ __launch_bounds__(256)
void attn_win(const _Float16* __restrict__ qkvall, _Float16* __restrict__ attall) {
    const int sb  = (blockIdx.x & 7) * 64 + (blockIdx.x >> 3);   // XCD swizzle
    const int wid = threadIdx.x >> 6;
    const int h   = threadIdx.x & 63;
    const int wflat = sb * 4 + wid;          // 0..2047
    const int ig  = (wflat & 127) + 4;       // 4..131 -> rows 16..527
    const int db  = wflat >> 7;              // 0..15
    const int b   = db & 7;
    const int dir = db >> 3;
    const int i0  = ig * 4;
    const int dlo = dir ? 0 : -17;
    const _Float16* qkv = qkvall + (size_t)dir * MROWS * 1536;
    _Float16* att = attall + (size_t)dir * MROWS * 512;
    const size_t rowb = (size_t)b * NSEQ;
    const float scale = 0.35355339059327373f;  // 1/sqrt(8)

    float q[4][8];
#pragma unroll
    for (int tq = 0; tq < 4; tq++) {
        const half8 q8 = *(const half8*)(qkv + (rowb + i0 + tq) * 1536 + h * 8);
#pragma unroll
        for (int d = 0; d < 8; d++) q[tq][d] = (float)q8[d];
    }

    float o[4][8] = {};
    float sum[4] = {};
    const int j0 = i0 + dlo;

#pragma unroll
    for (int jj = 0; jj < 21; jj++) {
        const int j = j0 + jj;
        if (j < 0 || j > NSEQ - 1) continue;   // wave-uniform branch
        const size_t jbase = (rowb + j) * 1536 + h * 8;
        const half8 k8 = *(const half8*)(qkv + jbase + 512);
        const half8 v8 = *(const half8*)(qkv + jbase + 1024);
        float kv[8], vv[8];
#pragma unroll
        for (int d = 0; d < 8; d++) { kv[d] = (float)k8[d]; vv[d] = (float)v8[d]; }
#pragma unroll
        for (int tq = 0; tq < 4; tq++) {
            if (jj < tq || jj > tq + 17) continue;  // compile-time prune
            float d = 0.f;
#pragma unroll
            for (int dd = 0; dd < 8; dd++) d = fmaf(q[tq][dd], kv[dd], d);
            const float p = __expf(d * scale);   // shift-free softmax (s is O(1))
            sum[tq] += p;
#pragma unroll
            for (int dd = 0; dd < 8; dd++) o[tq][dd] = fmaf(p, vv[dd], o[tq][dd]);
        }
    }

#pragma unroll
    for (int tq = 0; tq < 4; tq++) {
        const float inv = 1.f / sum[tq];
        half8 o16;
#pragma unroll
        for (int d = 0; d < 8; d++) o16[d] = (_Float16)(o[tq][d] * inv);
        *(half8*)&att[(rowb + i0 + tq) * 512 + h * 8] = o16;
    }
}

// ====== prep: fused weight convert (6 tensors) + pad-concat to f16 ======
__global__ void prep(const float* __restrict__ lq, const float* __restrict__ rq,
                     const float* __restrict__ lo, const float* __restrict__ ro,
                     const float* __restrict__ lh, const float* __restrict__ rh,
                     _Float16* __restrict__ wdst,
                     const float* __restrict__ inp,
                     const float* __restrict__ lp,
                     const float* __restrict__ rp,
                     _Float16* __restrict__ padX) {
    const int gb = blockIdx.x;
    if (gb < 4096) {
        int idx = gb * 256 + threadIdx.x;
        const float* src; int off;
        if      (idx < 196608) { src = lq; off = idx; }
        else if (idx < 393216) { src = rq; off = idx - 196608; }
        else if (idx < 458752) { src = lo; off = idx - 393216; }
        else if (idx < 524288) { src = ro; off = idx - 458752; }
        else if (idx < 786432) { src = lh; off = idx - 524288; }
        else                   { src = rh; off = idx - 786432; }
        const float4 v = ((const float4*)src)[off];
        half4 h = { (_Float16)v.x, (_Float16)v.y, (_Float16)v.z, (_Float16)v.w };
        ((half4*)wdst)[idx] = h;
    } else {
        int idx = (gb - 4096) * 256 + threadIdx.x;   // MROWS*128 total
        const int c4 = idx & 127;
        const int t  = idx >> 7;
        const int n = t % NSEQ;
        const int b = t / NSEQ;
        const float* src;
        if (n < WIDTH_)            src = lp + n * 512;
        else if (n < WIDTH_ + S_)  src = inp + ((size_t)(b * S_ + n - WIDTH_)) * 512;
        else                       src = rp + (n - WIDTH_ - S_) * 512;
        const float4 v = *(const float4*)(src + c4 * 4);
        half4 h = { (_Float16)v.x, (_Float16)v.y, (_Float16)v.z, (_Float16)v.w };
        *(half4*)&padX[(size_t)t * 512 + c4 * 4] = h;
    }
}

extern "C" void kernel_launch(void* const* d_in, const int* in_sizes, int n_in,
                              void* d_out, int out_size, void* d_ws, size_t ws_size,
                              hipStream_t stream) {
    const float* inputs    = (const float*)d_in[0];
    const float* left_pad  = (const float*)d_in[1];
    const float* right_pad = (const float*)d_in[2];
    const float* l_Wqkv = (const float*)d_in[3];
    const float* l_bqkv = (const float*)d_in[4];
    const float* l_Wo   = (const float*)d_in[5];
    const float* l_bo   = (const float*)d_in[6];
    const float* r_Wqkv = (const float*)d_in[7];
    const float* r_bqkv = (const float*)d_in[8];
    const float* r_Wo   = (const float*)d_in[9];
    const float* r_bo   = (const float*)d_in[10];
    const float* lhw_W  = (const float*)d_in[11];
    const float* lhw_b  = (const float*)d_in[12];
    const float* rhw_W  = (const float*)d_in[13];
    const float* rhw_b  = (const float*)d_in[14];

    float* out = (float*)d_out;
    _Float16* h = (_Float16*)d_ws;

    // f16 arena offsets (f16 units)
    _Float16* padX16 = h;                    // 2,228,224
    _Float16* w16    = h + 2228224;          // 4,194,304
    _Float16* lqkv16 = w16;
    _Float16* rqkv16 = w16 + 786432;
    _Float16* lWo16  = w16 + 1572864;
    _Float16* rWo16  = w16 + 1835008;
    _Float16* lhw16  = w16 + 2097152;
    _Float16* rhw16  = w16 + 3145728;
    _Float16* qkv16  = h + 6422528;          // 13,369,344 (2 dirs)
    _Float16* att16  = h + 19791872;         // 4,456,448  (2 dirs)
    _Float16* x16a   = h + 24248320;         // 4,194,304  (2 dirs) ping
    _Float16* x16b   = h + 28442624;         // 4,194,304  (2 dirs) pong

    float* out_all  = out;            // all_layers [1,B,S,2D]
    float* out_last = out + OUTHALF;  // last       [B,S,2D]

    // fused weight cvt + pad concat
    prep<<<6272, 256, 0, stream>>>(l_Wqkv, r_Wqkv, l_Wo, r_Wo, lhw_W, rhw_W, w16,
                                   inputs, left_pad, right_pad, padX16);

    // QKV both dirs: [4352,512] x [1536,512]^T -> f16 [2][4352,1536]
    gemm_qkv<<<dim3(12, 34, 2), 256, 0, stream>>>(
        padX16, lqkv16, rqkv16, l_bqkv, r_bqkv, qkv16);

    // windowed attention both dirs, live rows only -> att16 [2][4352,512]
    attn_win<<<dim3(512), 256, 0, stream>>>(qkv16, att16);

    // Wo + slice -> x16a (f16), 512 blocks (2/CU, no tail)
    gemm_wo<<<dim3(4, 64, 2), 256, 0, stream>>>(
        att16, lWo16, rWo16, l_bo, r_bo, x16a);

    // highway layer 1: x16a -> x16b
    gemm_hw<<<dim3(8, 32, 2), 256, 0, stream>>>(
        x16a, lhw16, rhw16, lhw_b, rhw_b, x16b, nullptr, nullptr);
    // highway layer 2: x16b -> out_last + out_all (f32)
    gemm_hw<<<dim3(8, 32, 2), 256, 0, stream>>>(
        x16b, lhw16 + 524288, rhw16 + 524288, lhw_b + 1024, rhw_b + 1024,
        nullptr, out_last, out_all);
}

// Round 10
// 183.618 us; speedup vs baseline: 1.0284x; 1.0005x over previous
//
#include <hip/hip_runtime.h>
#include <math.h>

#define B_ 8
#define S_ 512
#define D_ 512
#define WIDTH_ 16
#define NSEQ 544                 // S + 2*WIDTH
#define MROWS 4352               // B*NSEQ
#define MOUT 4096                // B*S
#define OUTHALF 4194304          // B*S*2D floats per output tensor

typedef _Float16 half8 __attribute__((ext_vector_type(8)));
typedef _Float16 half4 __attribute__((ext_vector_type(4)));
typedef float floatx4 __attribute__((ext_vector_type(4)));

// async global->LDS, 16B per lane, dest = wave-uniform base + lane*16
#define GLD16(g, l) __builtin_amdgcn_global_load_lds(                          \
    (const __attribute__((address_space(1))) void*)(g),                        \
    (__attribute__((address_space(3))) void*)(l), 16, 0, 0)

#define WAIT_VM(n)  asm volatile("s_waitcnt vmcnt(" #n ")" ::: "memory")
#define WAIT_LGKM0() asm volatile("s_waitcnt lgkmcnt(0)" ::: "memory")
#define BARRIER()                                                              \
    do {                                                                       \
        __builtin_amdgcn_s_barrier();                                          \
        asm volatile("" ::: "memory");                                         \
    } while (0)

__device__ __forceinline__ float sigmoidf_(float x) {
    return 1.f / (1.f + __expf(-x));
}

// XCD-contiguity swizzle: dispatch index d (round-robin over 8 XCDs) ->
// logical tile t = (d%8)*(nwg/8) + d/8 so each XCD gets a contiguous chunk.
// All grids here have nwg % 8 == 0 (bijective).
__device__ __forceinline__ void xcd_swz(const int nx, const int ny,
                                        int& bx, int& by, int& bz) {
    const int flat = blockIdx.x + nx * (blockIdx.y + ny * blockIdx.z);
    const int nwg  = nx * ny * 2;
    const int t2   = (flat & 7) * (nwg >> 3) + (flat >> 3);
    bz = t2 / (nx * ny);
    const int rem = t2 - bz * nx * ny;
    by = rem / nx;
    bx = rem - by * nx;
}

// ================= QKV GEMM: 128x128 tile, f16 out, dual-dir =================
// C16[z][m,n] = sum_k A[m,k]*B[z][n,k] + bias[z][n]
// grid (12, 34, 2), block 256.  Depth-2 counted-vmcnt pipeline (R3-proven).
// Epilogue: stage C-tile in LDS (reusing staging buffers) -> half8 stores.
__global__ __launch_bounds__(256)
void gemm_qkv(const _Float16* __restrict__ A,
              const _Float16* __restrict__ B0, const _Float16* __restrict__ B1,
              const float* __restrict__ bias0, const float* __restrict__ bias1,
              _Float16* __restrict__ C16) {
    const int lda = 512, ldb = 512, ldc = 1536;
    __shared__ _Float16 SH[16384];   // 32 KB: As[2][4096] | Bs[2][4096]; CT reuse
    int bx, by, bz;
    xcd_swz(12, 34, bx, by, bz);
    const int t    = threadIdx.x;
    const int wave = t >> 6;
    const int lane = t & 63;
    const int bm = by * 128;
    const int bn = bx * 128;
    const int z  = bz;
    const _Float16* B = z ? B1 : B0;
    const float* bias = z ? bias1 : bias0;
    _Float16* C = C16 + (size_t)z * MROWS * 1536;
    const int wm = (wave & 1) * 64;
    const int wn = (wave >> 1) * 64;

    const int inst = wave * 2;
    const int r0 = inst * 16 + (lane >> 2);   // 16 rows per GLD16 inst
    const int kf = (lane & 3) * 8;

    const _Float16* Ag0 = A + (size_t)(bm + r0) * lda + kf;
    const _Float16* Ag1 = Ag0 + (size_t)16 * lda;
    const _Float16* Bg0 = B + (size_t)(bn + r0) * ldb + kf;
    const _Float16* Bg1 = Bg0 + (size_t)16 * ldb;
    const int so = inst * 512;                // f16 offset inside one buffer

    const int fr = lane & 15;
    const int fq = (lane >> 4) * 8;

    floatx4 acc[4][4] = {};

#define QKV_STAGE(bf_, koff_)                                                  \
    do {                                                                       \
        GLD16(Ag0 + (koff_), &SH[(bf_) * 4096 + so]);                          \
        GLD16(Ag1 + (koff_), &SH[(bf_) * 4096 + so + 512]);                    \
        GLD16(Bg0 + (koff_), &SH[8192 + (bf_) * 4096 + so]);                   \
        GLD16(Bg1 + (koff_), &SH[8192 + (bf_) * 4096 + so + 512]);             \
    } while (0)

    QKV_STAGE(0, 0);
    QKV_STAGE(1, 32);

#pragma unroll
    for (int tt = 0; tt < 16; tt++) {
        const int c = tt & 1;
        if (tt == 15) WAIT_VM(0);
        else          WAIT_VM(4);
        BARRIER();
        half8 af[4], bf[4];
#pragma unroll
        for (int s = 0; s < 4; s++) {
            af[s] = *(const half8*)&SH[c * 4096 + (wm + s * 16 + fr) * 32 + fq];
            bf[s] = *(const half8*)&SH[8192 + c * 4096 + (wn + s * 16 + fr) * 32 + fq];
        }
        WAIT_LGKM0();
        BARRIER();
        if (tt + 2 < 16) QKV_STAGE(c, (tt + 2) * 32);
#pragma unroll
        for (int i = 0; i < 4; i++)
#pragma unroll
            for (int j = 0; j < 4; j++)
                acc[i][j] = __builtin_amdgcn_mfma_f32_16x16x32_f16(
                    af[i], bf[j], acc[i][j], 0, 0, 0);
    }
#undef QKV_STAGE

    // ---- coalesced epilogue: acc -> LDS (f16, +bias) -> half8 stores ----
    const int rq = (lane >> 4) * 4;
    const int cc = lane & 15;
#pragma unroll
    for (int i = 0; i < 4; i++) {
#pragma unroll
        for (int j = 0; j < 4; j++) {
            const int col = wn + j * 16 + cc;
            const float bv = bias[bn + col];
#pragma unroll
            for (int r = 0; r < 4; r++)
                SH[(wm + i * 16 + rq + r) * 128 + col] =
                    (_Float16)(acc[i][j][r] + bv);
        }
    }
    WAIT_LGKM0();
    BARRIER();
#pragma unroll
    for (int it = 0; it < 8; it++) {
        const int flat = it * 256 + t;
        const int row = flat >> 4;
        const int ch  = flat & 15;
        *(half8*)&C[(size_t)(bm + row) * ldc + bn + ch * 8] =
            *(const half8*)&SH[row * 128 + ch * 8];
    }
}

// ======== Wo GEMM: 64x128 tile, dual-dir, sliced-row A addressing ========
// grid (4, 64, 2) = 512 blocks = exactly 2/CU (no 32-block tail).
__global__ __launch_bounds__(256)
void gemm_wo(const _Float16* __restrict__ Aall,
             const _Float16* __restrict__ B0, const _Float16* __restrict__ B1,
             const float* __restrict__ bias0, const float* __restrict__ bias1,
             _Float16* __restrict__ x16base) { // +z*MOUT*512
    const int lda = 512, ldb = 512;
    __shared__ _Float16 As[2][64 * 32];     // 8 KB
    __shared__ _Float16 Bs[2][128 * 32];    // 16 KB
    int bx, by, bz;
    xcd_swz(4, 64, bx, by, bz);
    const int t    = threadIdx.x;
    const int wave = t >> 6;
    const int lane = t & 63;
    const int bm = by * 64;                 // x-space row base
    const int bn = bx * 128;
    const int z  = bz;
    const _Float16* A = Aall + (size_t)z * MROWS * 512;
    const _Float16* B = z ? B1 : B0;
    const float* bias = z ? bias1 : bias0;
    _Float16* x16 = x16base + (size_t)z * MOUT * 512;

    const int bb   = bm >> 9;               // batch index
    const int arow = bb * NSEQ + WIDTH_ + (bm & 511);   // att-space row base

    const int wm = (wave & 1) * 32;
    const int wn = (wave >> 1) * 64;

    const int rA = wave * 16 + (lane >> 2);
    const int rB = wave * 32 + (lane >> 2);
    const int kf = (lane & 3) * 8;

    const _Float16* Ag0 = A + (size_t)(arow + rA) * lda + kf;
    const _Float16* Bg0 = B + (size_t)(bn + rB) * ldb + kf;
    const _Float16* Bg1 = Bg0 + (size_t)16 * ldb;
    const int soA = wave * 512;
    const int soB = wave * 1024;

    const int fr = lane & 15;
    const int fq = (lane >> 4) * 8;

    floatx4 acc[2][4] = {};

#define WO_STAGE(bf_, koff_)                                                   \
    do {                                                                       \
        GLD16(Ag0 + (koff_), &As[bf_][soA]);                                   \
        GLD16(Bg0 + (koff_), &Bs[bf_][soB]);                                   \
        GLD16(Bg1 + (koff_), &Bs[bf_][soB + 512]);                             \
    } while (0)

    WO_STAGE(0, 0);
    WO_STAGE(1, 32);

#pragma unroll
    for (int tt = 0; tt < 16; tt++) {
        const int c = tt & 1;
        if (tt == 15) WAIT_VM(0);
        else          WAIT_VM(3);
        BARRIER();
        half8 af[2], bf[4];
#pragma unroll
        for (int s = 0; s < 2; s++)
            af[s] = *(const half8*)&As[c][(wm + s * 16 + fr) * 32 + fq];
#pragma unroll
        for (int s = 0; s < 4; s++)
            bf[s] = *(const half8*)&Bs[c][(wn + s * 16 + fr) * 32 + fq];
        WAIT_LGKM0();
        BARRIER();
        if (tt + 2 < 16) WO_STAGE(c, (tt + 2) * 32);
#pragma unroll
        for (int i = 0; i < 2; i++)
#pragma unroll
            for (int j = 0; j < 4; j++)
                acc[i][j] = __builtin_amdgcn_mfma_f32_16x16x32_f16(
                    af[i], bf[j], acc[i][j], 0, 0, 0);
    }
#undef WO_STAGE

    const int rq = (lane >> 4) * 4;
    const int cc = lane & 15;
#pragma unroll
    for (int i = 0; i < 2; i++) {
        const int rbase = bm + wm + i * 16 + rq;
#pragma unroll
        for (int r = 0; r < 4; r++) {
            const int m = rbase + r;        // always a valid x row
#pragma unroll
            for (int j = 0; j < 4; j++) {
                const int col = bn + wn + j * 16 + cc;
                x16[(size_t)m * 512 + col] = (_Float16)(acc[i][j][r] + bias[col]);
            }
        }
    }
}

// ==== Highway GEMM: 128x64 tile, dual-N (nonlin+gate), fused combine ====
// grid (8, 32, 2), block 256.  R3-proven (unchanged from R9).
__global__ __launch_bounds__(256)
void gemm_hw(const _Float16* __restrict__ x16inbase,
             const _Float16* __restrict__ W0, const _Float16* __restrict__ W1,
             const float* __restrict__ b0, const float* __restrict__ b1,
             _Float16* __restrict__ x16outbase,   // null on last layer
             float* __restrict__ outlastbase,     // last layer only
             float* __restrict__ outallbase) {    // last layer only
    const int lda = 512, ldb = 512;
    __shared__ _Float16 SA[8192];          // As[2][4096] = 16 KB; CT reuse
    __shared__ _Float16 Bn[2][64 * 32];    // 8 KB
    __shared__ _Float16 Bg[2][64 * 32];    // 8 KB
    int bx, by, bz;
    xcd_swz(8, 32, bx, by, bz);
    const int t    = threadIdx.x;
    const int wave = t >> 6;
    const int lane = t & 63;
    const int bm = by * 128;
    const int bn = bx * 64;     // col block within [0,512)
    const int z  = bz;
    const _Float16* A = x16inbase + (size_t)z * MOUT * 512;
    const _Float16* W = z ? W1 : W0;
    const float* bias = z ? b1 : b0;
    _Float16* x16out = x16outbase ? x16outbase + (size_t)z * MOUT * 512 : nullptr;

    const int wm = (wave & 1) * 64;
    const int wn = (wave >> 1) * 32;

    const int rA = wave * 32 + (lane >> 2);
    const int rB = wave * 16 + (lane >> 2);
    const int kf = (lane & 3) * 8;

    const _Float16* Ag0 = A + (size_t)(bm + rA) * lda + kf;
    const _Float16* Ag1 = Ag0 + (size_t)16 * lda;
    const _Float16* Bn0 = W + (size_t)(bn + rB) * ldb + kf;
    const _Float16* Bg0 = W + (size_t)(512 + bn + rB) * ldb + kf;
    const int soA = wave * 1024;
    const int soB = wave * 512;

    const int fr = lane & 15;
    const int fq = (lane >> 4) * 8;

    floatx4 accn[4][2] = {};
    floatx4 accg[4][2] = {};

#define HW_STAGE(bf_, koff_)                                                   \
    do {                                                                       \
        GLD16(Ag0 + (koff_), &SA[(bf_) * 4096 + soA]);                         \
        GLD16(Ag1 + (koff_), &SA[(bf_) * 4096 + soA + 512]);                   \
        GLD16(Bn0 + (koff_), &Bn[bf_][soB]);                                   \
        GLD16(Bg0 + (koff_), &Bg[bf_][soB]);                                   \
    } while (0)

    HW_STAGE(0, 0);
    HW_STAGE(1, 32);

#pragma unroll
    for (int tt = 0; tt < 16; tt++) {
        const int c = tt & 1;
        if (tt == 15) WAIT_VM(0);
        else          WAIT_VM(4);
        BARRIER();
        half8 af[4], bnf[2], bgf[2];
#pragma unroll
        for (int s = 0; s < 4; s++)
            af[s] = *(const half8*)&SA[c * 4096 + (wm + s * 16 + fr) * 32 + fq];
#pragma unroll
        for (int s = 0; s < 2; s++) {
            bnf[s] = *(const half8*)&Bn[c][(wn + s * 16 + fr) * 32 + fq];
            bgf[s] = *(const half8*)&Bg[c][(wn + s * 16 + fr) * 32 + fq];
        }
        WAIT_LGKM0();
        BARRIER();
        if (tt + 2 < 16) HW_STAGE(c, (tt + 2) * 32);
#pragma unroll
        for (int i = 0; i < 4; i++)
#pragma unroll
            for (int j = 0; j < 2; j++) {
                accn[i][j] = __builtin_amdgcn_mfma_f32_16x16x32_f16(
                    af[i], bnf[j], accn[i][j], 0, 0, 0);
                accg[i][j] = __builtin_amdgcn_mfma_f32_16x16x32_f16(
                    af[i], bgf[j], accg[i][j], 0, 0, 0);
            }
    }
#undef HW_STAGE

    const int rq = (lane >> 4) * 4;
    const int cc = lane & 15;
    if (x16out) {
        // combine -> LDS f16 tile [128][64] -> coalesced stores
#pragma unroll
        for (int i = 0; i < 4; i++) {
#pragma unroll
            for (int j = 0; j < 2; j++) {
                const int col = wn + j * 16 + cc;
                const float bnl = bias[bn + col];
                const float bgt = bias[512 + bn + col];
#pragma unroll
                for (int r = 0; r < 4; r++) {
                    const int row = wm + i * 16 + rq + r;
                    const float nl = fmaxf(accn[i][j][r] + bnl, 0.f);
                    const float g  = sigmoidf_(accg[i][j][r] + bgt);
                    const float xo = (float)A[(size_t)(bm + row) * 512 + bn + col];
                    SA[row * 64 + col] = (_Float16)(g * xo + (1.f - g) * nl);
                }
            }
        }
        WAIT_LGKM0();
        BARRIER();
#pragma unroll
        for (int it = 0; it < 4; it++) {
            const int flat = it * 256 + t;
            const int row = flat >> 3;
            const int ch  = flat & 7;
            *(half8*)&x16out[(size_t)(bm + row) * 512 + bn + ch * 8] =
                *(const half8*)&SA[row * 64 + ch * 8];
        }
    } else {
        float* outlast = outlastbase + z * 512;
        float* outall  = outallbase  + z * 512;
#pragma unroll
        for (int i = 0; i < 4; i++) {
            const int rbase = bm + wm + i * 16 + rq;
#pragma unroll
            for (int j = 0; j < 2; j++) {
                const int col = bn + wn + j * 16 + cc;
                const float bnl = bias[col];
                const float bgt = bias[512 + col];
#pragma unroll
                for (int r = 0; r < 4; r++) {
                    const int row = rbase + r;
                    const float nl = fmaxf(accn[i][j][r] + bnl, 0.f);
                    const float g  = sigmoidf_(accg[i][j][r] + bgt);
                    const float xo = (float)A[(size_t)row * 512 + col];
                    const float v  = g * xo + (1.f - g) * nl;
                    outlast[(size_t)row * 1024 + col] = v;
                    outall[(size_t)row * 1024 + col] = v;
                }
            }
        }
    }
}

// ---- windowed attention (live rows) + folded Wo/highway weight convert ----
// blocks [0,512): attn, TI=4, rows [16,528)/batch, 2 blocks/CU (R9-proven).
// blocks [512,3072): f32->f16 convert of Wo + highway weights (not needed
// until the NEXT dispatch) -- fills the idle CU slots under latency-bound
// attn instead of occupying a serial slice of the prep dispatch.
__global__ __launch_bounds__(256)
void attn_win(const _Float16* __restrict__ qkvall, _Float16* __restrict__ attall,
              const float* __restrict__ lo, const float* __restrict__ ro,
              const float* __restrict__ lh, const float* __restrict__ rh,
              _Float16* __restrict__ wdst) {
    if (blockIdx.x >= 512) {
        // weight convert: original prep idx space [393216, 1048576) float4s
        const int idx = (blockIdx.x - 512) * 256 + threadIdx.x + 393216;
        const float* src; int off;
        if      (idx < 458752) { src = lo; off = idx - 393216; }
        else if (idx < 524288) { src = ro; off = idx - 458752; }
        else if (idx < 786432) { src = lh; off = idx - 524288; }
        else                   { src = rh; off = idx - 786432; }
        const float4 v = ((const float4*)src)[off];
        half4 h = { (_Float16)v.x, (_Float16)v.y, (_Float16)v.z, (_Float16)v.w };
        ((half4*)wdst)[idx] = h;
        return;
    }
    const int sb  = (blockIdx.x & 7) * 64 + (blockIdx.x >> 3);   // XCD swizzle
    const int wid = threadIdx.x >> 6;
    const int h   = threadIdx.x & 63;
    const int wflat = sb * 4 + wid;          // 0..2047
    const int ig  = (wflat & 127) + 4;       // 4..131 -> rows 16..527
    const int db  = wflat >> 7;              // 0..15
    const int b   = db & 7;
    const int dir = db >> 3;
    const int i0  = ig * 4;
    const int dlo = dir ? 0 : -17;
    const _Float16* qkv = qkvall + (size_t)dir * MROWS * 1536;
    _Float16* att = attall + (size_t)dir * MROWS * 512;
    const size_t rowb = (size_t)b * NSEQ;
    const float scale = 0.35355339059327373f;  // 1/sqrt(8)

    float q[4][8];
#pragma unroll
    for (int tq = 0; tq < 4; tq++) {
        const half8 q8 = *(const half8*)(qkv + (rowb + i0 + tq) * 1536 + h * 8);
#pragma unroll
        for (int d = 0; d < 8; d++) q[tq][d] = (float)q8[d];
    }

    float o[4][8] = {};
    float sum[4] = {};
    const int j0 = i0 + dlo;

#pragma unroll
    for (int jj = 0; jj < 21; jj++) {
        const int j = j0 + jj;
        if (j < 0 || j > NSEQ - 1) continue;   // wave-uniform branch
        const size_t jbase = (rowb + j) * 1536 + h * 8;
        const half8 k8 = *(const half8*)(qkv + jbase + 512);
        const half8 v8 = *(const half8*)(qkv + jbase + 1024);
        float kv[8], vv[8];
#pragma unroll
        for (int d = 0; d < 8; d++) { kv[d] = (float)k8[d]; vv[d] = (float)v8[d]; }
#pragma unroll
        for (int tq = 0; tq < 4; tq++) {
            if (jj < tq || jj > tq + 17) continue;  // compile-time prune
            float d = 0.f;
#pragma unroll
            for (int dd = 0; dd < 8; dd++) d = fmaf(q[tq][dd], kv[dd], d);
            const float p = __expf(d * scale);   // shift-free softmax (s is O(1))
            sum[tq] += p;
#pragma unroll
            for (int dd = 0; dd < 8; dd++) o[tq][dd] = fmaf(p, vv[dd], o[tq][dd]);
        }
    }

#pragma unroll
    for (int tq = 0; tq < 4; tq++) {
        const float inv = 1.f / sum[tq];
        half8 o16;
#pragma unroll
        for (int d = 0; d < 8; d++) o16[d] = (_Float16)(o[tq][d] * inv);
        *(half8*)&att[(rowb + i0 + tq) * 512 + h * 8] = o16;
    }
}

// ====== prep_early: QKV weight convert + pad-concat (qkv's inputs only) ======
// blocks [0,1536): qkv weights (lq, rq = 393,216 float4s);
// blocks [1536,3712): pad-concat (MROWS*128 float4s).
__global__ void prep_early(const float* __restrict__ lq,
                           const float* __restrict__ rq,
                           _Float16* __restrict__ wdst,
                           const float* __restrict__ inp,
                           const float* __restrict__ lp,
                           const float* __restrict__ rp,
                           _Float16* __restrict__ padX) {
    const int gb = blockIdx.x;
    if (gb < 1536) {
        int idx = gb * 256 + threadIdx.x;
        const float* src; int off;
        if (idx < 196608) { src = lq; off = idx; }
        else              { src = rq; off = idx - 196608; }
        const float4 v = ((const float4*)src)[off];
        half4 h = { (_Float16)v.x, (_Float16)v.y, (_Float16)v.z, (_Float16)v.w };
        ((half4*)wdst)[idx] = h;
    } else {
        int idx = (gb - 1536) * 256 + threadIdx.x;   // MROWS*128 total
        const int c4 = idx & 127;
        const int t  = idx >> 7;
        const int n = t % NSEQ;
        const int b = t / NSEQ;
        const float* src;
        if (n < WIDTH_)            src = lp + n * 512;
        else if (n < WIDTH_ + S_)  src = inp + ((size_t)(b * S_ + n - WIDTH_)) * 512;
        else                       src = rp + (n - WIDTH_ - S_) * 512;
        const float4 v = *(const float4*)(src + c4 * 4);
        half4 h = { (_Float16)v.x, (_Float16)v.y, (_Float16)v.z, (_Float16)v.w };
        *(half4*)&padX[(size_t)t * 512 + c4 * 4] = h;
    }
}

extern "C" void kernel_launch(void* const* d_in, const int* in_sizes, int n_in,
                              void* d_out, int out_size, void* d_ws, size_t ws_size,
                              hipStream_t stream) {
    const float* inputs    = (const float*)d_in[0];
    const float* left_pad  = (const float*)d_in[1];
    const float* right_pad = (const float*)d_in[2];
    const float* l_Wqkv = (const float*)d_in[3];
    const float* l_bqkv = (const float*)d_in[4];
    const float* l_Wo   = (const float*)d_in[5];
    const float* l_bo   = (const float*)d_in[6];
    const float* r_Wqkv = (const float*)d_in[7];
    const float* r_bqkv = (const float*)d_in[8];
    const float* r_Wo   = (const float*)d_in[9];
    const float* r_bo   = (const float*)d_in[10];
    const float* lhw_W  = (const float*)d_in[11];
    const float* lhw_b  = (const float*)d_in[12];
    const float* rhw_W  = (const float*)d_in[13];
    const float* rhw_b  = (const float*)d_in[14];

    float* out = (float*)d_out;
    _Float16* h = (_Float16*)d_ws;

    // f16 arena offsets (f16 units)
    _Float16* padX16 = h;                    // 2,228,224
    _Float16* w16    = h + 2228224;          // 4,194,304
    _Float16* lqkv16 = w16;
    _Float16* rqkv16 = w16 + 786432;
    _Float16* lWo16  = w16 + 1572864;
    _Float16* rWo16  = w16 + 1835008;
    _Float16* lhw16  = w16 + 2097152;
    _Float16* rhw16  = w16 + 3145728;
    _Float16* qkv16  = h + 6422528;          // 13,369,344 (2 dirs)
    _Float16* att16  = h + 19791872;         // 4,456,448  (2 dirs)
    _Float16* x16a   = h + 24248320;         // 4,194,304  (2 dirs) ping
    _Float16* x16b   = h + 28442624;         // 4,194,304  (2 dirs) pong

    float* out_all  = out;            // all_layers [1,B,S,2D]
    float* out_last = out + OUTHALF;  // last       [B,S,2D]

    // qkv weights cvt + pad concat (only what gemm_qkv needs)
    prep_early<<<3712, 256, 0, stream>>>(l_Wqkv, r_Wqkv, w16,
                                         inputs, left_pad, right_pad, padX16);

    // QKV both dirs: [4352,512] x [1536,512]^T -> f16 [2][4352,1536]
    gemm_qkv<<<dim3(12, 34, 2), 256, 0, stream>>>(
        padX16, lqkv16, rqkv16, l_bqkv, r_bqkv, qkv16);

    // windowed attention (live rows) + folded Wo/hw weight convert
    attn_win<<<dim3(3072), 256, 0, stream>>>(qkv16, att16,
                                             l_Wo, r_Wo, lhw_W, rhw_W, w16);

    // Wo + slice -> x16a (f16), 512 blocks (2/CU, no tail)
    gemm_wo<<<dim3(4, 64, 2), 256, 0, stream>>>(
        att16, lWo16, rWo16, l_bo, r_bo, x16a);

    // highway layer 1: x16a -> x16b
    gemm_hw<<<dim3(8, 32, 2), 256, 0, stream>>>(
        x16a, lhw16, rhw16, lhw_b, rhw_b, x16b, nullptr, nullptr);
    // highway layer 2: x16b -> out_last + out_all (f32)
    gemm_hw<<<dim3(8, 32, 2), 256, 0, stream>>>(
        x16b, lhw16 + 524288, rhw16 + 524288, lhw_b + 1024, rhw_b + 1024,
        nullptr, out_last, out_all);
}